// Round 1
// 626.636 us; speedup vs baseline: 1.1096x; 1.1096x over previous
//
#include <hip/hip_runtime.h>
#include <hip/hip_bf16.h>

// ---------------- problem constants ----------------
#define BATCH   512
#define NUM_ENT 100000
#define EDIM    200
#define KPAD    224         // EDIM padded to multiple of 32
#define OCH     32          // conv out channels
#define OH      8
#define OW      18
#define FCK     4608        // 32*8*18
#define EPSV    1e-5f
#define KSPLIT  4           // k4 K-split factor (K chunk = 1152)

// ---------------- ws layout (float offsets) ----------------
#define WS0   0        // [2]    bn0: mean, rs*g0
#define BN1   8        // [64]   bn1: scale[32], shift[32]
#define K1P   512      // [128]  bn0 per-block partials
#define K3P   704      // [512]  bn1 per-block partials (256 blocks x {sum,sumsq})
#define YCOFF 2048     // [512*32*8*18] = 2359296 -> ends 2361344
#define PART  2361344  // [KSPLIT*512*200] = 409600 -> ends 2770944 (11.08 MB)
// A hi/lo (bf16) overlap the yc region (yc dead after k4):
#define AHI   2048     // 512*224 ushorts = 57344 floats -> ends 59392
#define ALO   59392    // 512*224 ushorts -> ends 116736 (< PART, no overlap)

typedef short bf16x8 __attribute__((ext_vector_type(8)));
typedef float f32x4  __attribute__((ext_vector_type(4)));

__device__ __forceinline__ float sigf(float x) {
    return 1.0f / (1.0f + __expf(-x));
}

__device__ __forceinline__ unsigned short bf16_rn(float v) {
    unsigned int u = __float_as_uint(v);
    unsigned int r = (u + 0x7FFFu + ((u >> 16) & 1u)) >> 16;
    return (unsigned short)r;
}

__device__ __forceinline__ void split_bf16(float v, unsigned short& hi, unsigned short& lo) {
    hi = bf16_rn(v);
    float hf = __uint_as_float(((unsigned int)hi) << 16);
    lo = bf16_rn(v - hf);
}

// k1a: bn0 partial sums over gathered embeddings
__global__ __launch_bounds__(256) void k1a_bn0(const int* __restrict__ e1,
                                               const float* __restrict__ emb,
                                               float* __restrict__ ws) {
    __shared__ float red[256], red2[256];
    int tid = threadIdx.x;
    int base = blockIdx.x * 1600;
    float s = 0.f, s2 = 0.f;
    for (int i = base + tid; i < base + 1600; i += 256) {
        int b = i / EDIM;
        int k = i - b * EDIM;
        float v = emb[(size_t)e1[b] * EDIM + k];
        s += v; s2 += v * v;
    }
    red[tid] = s; red2[tid] = s2;
    __syncthreads();
    for (int off = 128; off; off >>= 1) {
        if (tid < off) { red[tid] += red[tid + off]; red2[tid] += red2[tid + off]; }
        __syncthreads();
    }
    if (tid == 0) {
        ws[K1P + 2 * blockIdx.x + 0] = red[0];
        ws[K1P + 2 * blockIdx.x + 1] = red2[0];
    }
}

// k1b: finalize bn0
__global__ __launch_bounds__(64) void k1b_bn0(const float* __restrict__ g0,
                                              float* __restrict__ ws) {
    __shared__ float red[64], red2[64];
    int tid = threadIdx.x;
    red[tid]  = ws[K1P + 2 * tid + 0];
    red2[tid] = ws[K1P + 2 * tid + 1];
    __syncthreads();
    for (int off = 32; off; off >>= 1) {
        if (tid < off) { red[tid] += red[tid + off]; red2[tid] += red2[tid + off]; }
        __syncthreads();
    }
    if (tid == 0) {
        const float inv = 1.0f / (BATCH * EDIM);
        float m = red[0] * inv;
        float var = red2[0] * inv - m * m;
        ws[WS0 + 0] = m;
        ws[WS0 + 1] = rsqrtf(var + EPSV) * g0[0];
    }
}

// k2: relation-indexed 3x3 conv on bn0-normalized x
__global__ __launch_bounds__(256) void k2_conv(const int* __restrict__ e1,
                                               const int* __restrict__ rel,
                                               const float* __restrict__ emb,
                                               const float* __restrict__ cw,
                                               const float* __restrict__ cb,
                                               const float* __restrict__ b0,
                                               float* __restrict__ ws) {
    __shared__ float xs[EDIM];
    __shared__ float wsh[OCH * 9];
    __shared__ float bsh[OCH];
    int b = blockIdx.x, tid = threadIdx.x;
    float m = ws[WS0 + 0], s = ws[WS0 + 1], b0v = b0[0];
    int r = rel[b];
    if (tid < EDIM) xs[tid] = fmaf(emb[(size_t)e1[b] * EDIM + tid] - m, s, b0v);
    for (int i = tid; i < OCH * 9; i += 256) wsh[i] = cw[(size_t)r * OCH * 9 + i];
    if (tid < OCH) bsh[tid] = cb[r * OCH + tid];
    __syncthreads();
    int o = tid >> 3, h = tid & 7;
    float w0 = wsh[o*9+0], w1 = wsh[o*9+1], w2 = wsh[o*9+2];
    float w3 = wsh[o*9+3], w4 = wsh[o*9+4], w5 = wsh[o*9+5];
    float w6 = wsh[o*9+6], w7 = wsh[o*9+7], w8 = wsh[o*9+8];
    float bias = bsh[o];
    float* yout = ws + YCOFF + ((size_t)b * OCH + o) * (OH * OW) + h * OW;
    const float* r0 = &xs[(h + 0) * 20];
    const float* r1 = &xs[(h + 1) * 20];
    const float* r2 = &xs[(h + 2) * 20];
    #pragma unroll
    for (int wd = 0; wd < OW; wd++) {
        float acc = bias;
        acc = fmaf(r0[wd+0], w0, acc); acc = fmaf(r0[wd+1], w1, acc); acc = fmaf(r0[wd+2], w2, acc);
        acc = fmaf(r1[wd+0], w3, acc); acc = fmaf(r1[wd+1], w4, acc); acc = fmaf(r1[wd+2], w5, acc);
        acc = fmaf(r2[wd+0], w6, acc); acc = fmaf(r2[wd+1], w7, acc); acc = fmaf(r2[wd+2], w8, acc);
        yout[wd] = acc;
    }
}

// k3a: bn1 partial stats — 8 slices per channel, 256 blocks
__global__ __launch_bounds__(256) void k3a_bn1(float* __restrict__ ws) {
    __shared__ float red[256], red2[256];
    int o = blockIdx.x >> 3, sl = blockIdx.x & 7;
    int tid = threadIdx.x;
    const float* yc = ws + YCOFF;
    const int per = (BATCH * OH * OW) / 8;   // 9216
    float s = 0.f, s2 = 0.f;
    for (int i = sl * per + tid; i < (sl + 1) * per; i += 256) {
        int b = i / (OH * OW);
        int p = i - b * (OH * OW);
        float v = yc[((size_t)b * OCH + o) * (OH * OW) + p];
        s += v; s2 += v * v;
    }
    red[tid] = s; red2[tid] = s2;
    __syncthreads();
    for (int off = 128; off; off >>= 1) {
        if (tid < off) { red[tid] += red[tid + off]; red2[tid] += red2[tid + off]; }
        __syncthreads();
    }
    if (tid == 0) {
        ws[K3P + 2 * blockIdx.x + 0] = red[0];
        ws[K3P + 2 * blockIdx.x + 1] = red2[0];
    }
}

// k3b: finalize bn1 -> scale/shift
__global__ __launch_bounds__(256) void k3b_bn1(const float* __restrict__ g1,
                                               const float* __restrict__ b1,
                                               float* __restrict__ ws) {
    __shared__ float rs[256], rq[256];
    int tid = threadIdx.x;
    rs[tid] = ws[K3P + 2 * tid + 0];
    rq[tid] = ws[K3P + 2 * tid + 1];
    __syncthreads();
    if (tid < OCH) {
        float sm = 0.f, sq = 0.f;
        #pragma unroll
        for (int sl = 0; sl < 8; sl++) { sm += rs[tid * 8 + sl]; sq += rq[tid * 8 + sl]; }
        const float inv = 1.0f / (BATCH * OH * OW);
        float m = sm * inv;
        float var = sq * inv - m * m;
        float a = rsqrtf(var + EPSV) * g1[tid];
        ws[BN1 + tid] = a;
        ws[BN1 + 32 + tid] = b1[tid] - m * a;
    }
}

// k4: FC GEMM partials (fp32, 64x64 tile, 4x4/thread, K-split)
__global__ __launch_bounds__(256) void k4_fc(float* __restrict__ ws,
                                             const float* __restrict__ fcw) {
    __shared__ float As[16][68];
    __shared__ float Bs[16][68];
    const float* yc = ws + YCOFF;
    const float* bn1p = ws + BN1;
    int tid = threadIdx.x;
    int tx = tid & 15, ty = tid >> 4;
    int j0 = blockIdx.x * 64;
    int m0 = blockIdx.y * 64;
    int kbase = blockIdx.z * (FCK / KSPLIT);
    float* part = ws + PART + (size_t)blockIdx.z * BATCH * EDIM;
    float acc[4][4];
    #pragma unroll
    for (int i = 0; i < 4; i++)
        #pragma unroll
        for (int j = 0; j < 4; j++) acc[i][j] = 0.f;

    for (int kc = 0; kc < FCK / KSPLIT; kc += 16) {
        for (int idx = tid; idx < 1024; idx += 256) {
            int k = idx & 15, mm = idx >> 4;
            int gk = kbase + kc + k;
            int o = gk / 144;
            float v = yc[(size_t)(m0 + mm) * FCK + gk];
            v = fmaf(v, bn1p[o], bn1p[32 + o]);
            As[k][mm] = v > 0.f ? v : 0.f;
        }
        for (int idx = tid; idx < 1024; idx += 256) {
            int k = idx & 15, jj = idx >> 4;
            int gj = j0 + jj;
            Bs[k][jj] = (gj < EDIM) ? fcw[(size_t)gj * FCK + kbase + kc + k] : 0.f;
        }
        __syncthreads();
        #pragma unroll
        for (int kk = 0; kk < 16; kk++) {
            float4 a = *(const float4*)&As[kk][ty * 4];
            float4 b = *(const float4*)&Bs[kk][tx * 4];
            float av[4] = {a.x, a.y, a.z, a.w};
            float bv[4] = {b.x, b.y, b.z, b.w};
            #pragma unroll
            for (int i = 0; i < 4; i++)
                #pragma unroll
                for (int j = 0; j < 4; j++)
                    acc[i][j] = fmaf(av[i], bv[j], acc[i][j]);
        }
        __syncthreads();
    }
    #pragma unroll
    for (int i = 0; i < 4; i++) {
        int m = m0 + ty * 4 + i;
        #pragma unroll
        for (int j = 0; j < 4; j++) {
            int gj = j0 + tx * 4 + j;
            if (gj < EDIM) part[m * EDIM + gj] = acc[i][j];
        }
    }
}

// k5: y2 = sum_z part + fc_b; bn2; A = relu(bn2(y2)) split to bf16 hi/lo [512][224]
__global__ __launch_bounds__(256) void k5_bn2(const float* __restrict__ g2,
                                              const float* __restrict__ b2,
                                              const float* __restrict__ fcb,
                                              float* __restrict__ ws) {
    unsigned short* gAh = (unsigned short*)(ws + AHI);
    unsigned short* gAl = (unsigned short*)(ws + ALO);
    int j = blockIdx.x, tid = threadIdx.x;
    if (j >= EDIM) {   // zero padding columns 200..223
        for (int b = tid; b < BATCH; b += 256) {
            gAh[(size_t)b * KPAD + j] = 0;
            gAl[(size_t)b * KPAD + j] = 0;
        }
        return;
    }
    __shared__ float red[256], red2[256];
    __shared__ float ss[2];
    const float* part = ws + PART;
    float bias = fcb[j];
    float v0 = bias, v1 = bias;
    #pragma unroll
    for (int z = 0; z < KSPLIT; z++) {
        v0 += part[(size_t)z * BATCH * EDIM + tid * EDIM + j];
        v1 += part[(size_t)z * BATCH * EDIM + (tid + 256) * EDIM + j];
    }
    red[tid] = v0 + v1; red2[tid] = v0 * v0 + v1 * v1;
    __syncthreads();
    for (int off = 128; off; off >>= 1) {
        if (tid < off) { red[tid] += red[tid + off]; red2[tid] += red2[tid + off]; }
        __syncthreads();
    }
    if (tid == 0) {
        const float inv = 1.0f / BATCH;
        float m = red[0] * inv;
        float var = red2[0] * inv - m * m;
        float a = rsqrtf(var + EPSV) * g2[j];
        ss[0] = a;
        ss[1] = b2[j] - m * a;
    }
    __syncthreads();
    float a = ss[0], s = ss[1];
    float r0 = fmaf(v0, a, s); r0 = r0 > 0.f ? r0 : 0.f;
    float r1 = fmaf(v1, a, s); r1 = r1 > 0.f ? r1 : 0.f;
    unsigned short h, l;
    split_bf16(r0, h, l);
    gAh[(size_t)tid * KPAD + j] = h;  gAl[(size_t)tid * KPAD + j] = l;
    split_bf16(r1, h, l);
    gAh[(size_t)(tid + 256) * KPAD + j] = h;  gAl[(size_t)(tid + 256) * KPAD + j] = l;
}

// k6: logits = sigmoid( A @ emb^T + bias_e ), split-bf16 3-pass MFMA.
// NEW structure: ONE barrier per block, zero barriers in the K-loop.
//  - block tile = 128 ents (n) x 256 batch rows (m); grid 782*2 = 1564, 512 thr / 8 waves
//  - full B-tile (128 x 224 k) staged to LDS ONCE as split bf16 hi/lo in frag-order
//    (112 KB LDS -> 1 block/CU, 2 waves/SIMD); lane-linear writes + contiguous-1KB
//    wave reads -> zero bank conflicts
//  - A hi/lo fragments loaded per-lane DIRECTLY from global (A = 458 KB, L2-resident)
//  - bijective XCD-chunked swizzle (1564 = 8*195+4) pairs the two m-blocks of each
//    n-tile on one XCD so the fp32 emb tile is fetched from HBM once
// FP accumulation order identical to previous version -> bit-identical output.
__global__ __launch_bounds__(512, 2) void k6_gemm(const float* __restrict__ ws,
                                                  const float* __restrict__ emb,
                                                  const float* __restrict__ be,
                                                  float* __restrict__ out) {
    __shared__ unsigned short Bh[28672];   // 57344 B
    __shared__ unsigned short Bl[28672];   // 57344 B
    const unsigned short* gAh = (const unsigned short*)(ws + AHI);
    const unsigned short* gAl = (const unsigned short*)(ws + ALO);
    int tid = threadIdx.x;

    // XCD-chunked bijective swizzle (m204 formula): nwg=1564, q=195, r=4
    int orig = blockIdx.x;
    const int Q = 195, R = 4;
    int xcd = orig & 7, lin = orig >> 3;
    int wid = (xcd < R ? xcd * (Q + 1) : R * (Q + 1) + (xcd - R) * Q) + lin;
    int n0 = (wid >> 1) * 128;
    int m0 = (wid & 1) * 256;

    // ---- stage full B tile: 128 ents x 28 k-chunks of 8, fp32 -> split hi/lo ----
    // LDS slot s = (g*28 + kch)*16 + col  holds row rr = g*16+col, k = kch*8..+8
    // (frag-order: a wave's ds_read_b128 at fixed (g, kc) covers 1 KB contiguous)
    for (int idx = tid; idx < 3584; idx += 512) {      // 3584 = 7 * 512, 7 iters
        int col = idx & 15;
        int t   = idx >> 4;          // g*28 + kch
        int g   = t / 28;
        int kch = t - g * 28;
        int rr  = g * 16 + col;
        int gn  = n0 + rr;
        float4 va = {0.f, 0.f, 0.f, 0.f};
        float4 vb = {0.f, 0.f, 0.f, 0.f};
        if (gn < NUM_ENT && kch < 25) {                // 25*8 = 200 = EDIM exactly
            const float* row = &emb[(size_t)gn * EDIM + kch * 8];
            va = *(const float4*)row;
            vb = *(const float4*)(row + 4);
        }
        unsigned short h0,h1,h2,h3,h4,h5,h6,h7, l0,l1,l2,l3,l4,l5,l6,l7;
        split_bf16(va.x, h0, l0); split_bf16(va.y, h1, l1);
        split_bf16(va.z, h2, l2); split_bf16(va.w, h3, l3);
        split_bf16(vb.x, h4, l4); split_bf16(vb.y, h5, l5);
        split_bf16(vb.z, h6, l6); split_bf16(vb.w, h7, l7);
        uint4 uh, ul;
        uh.x = (unsigned)h0 | ((unsigned)h1 << 16);
        uh.y = (unsigned)h2 | ((unsigned)h3 << 16);
        uh.z = (unsigned)h4 | ((unsigned)h5 << 16);
        uh.w = (unsigned)h6 | ((unsigned)h7 << 16);
        ul.x = (unsigned)l0 | ((unsigned)l1 << 16);
        ul.y = (unsigned)l2 | ((unsigned)l3 << 16);
        ul.z = (unsigned)l4 | ((unsigned)l5 << 16);
        ul.w = (unsigned)l6 | ((unsigned)l7 << 16);
        *(uint4*)&Bh[idx * 8] = uh;
        *(uint4*)&Bl[idx * 8] = ul;
    }
    __syncthreads();                                   // the ONLY barrier

    // ---- compute: wave = (mq in [0,4)) x (nhalf in [0,2)); 64m x 64n per wave ----
    int lane = tid & 63, col = lane & 15, quad = lane >> 4;
    int wave = tid >> 6;
    int nhalf = wave & 1, mq = wave >> 1;

    f32x4 acc[4][4];
    #pragma unroll
    for (int i = 0; i < 4; i++)
        #pragma unroll
        for (int j = 0; j < 4; j++)
            acc[i][j] = (f32x4){0.f, 0.f, 0.f, 0.f};

    int arow = m0 + mq * 64 + col;
    int gbase = nhalf * 4;

    for (int kc = 0; kc < KPAD; kc += 32) {            // 7 iters, no barriers
        bf16x8 ah[4], al[4], bh[4], bl[4];
        #pragma unroll
        for (int i = 0; i < 4; i++) {
            size_t aoff = (size_t)(arow + i * 16) * KPAD + kc + quad * 8;
            ah[i] = *(const bf16x8*)&gAh[aoff];
            al[i] = *(const bf16x8*)&gAl[aoff];
        }
        #pragma unroll
        for (int j = 0; j < 4; j++) {
            int boff = (((gbase + j) * 28) + (kc >> 3) + quad) * 128 + col * 8;
            bh[j] = *(const bf16x8*)&Bh[boff];
            bl[j] = *(const bf16x8*)&Bl[boff];
        }
        #pragma unroll
        for (int i = 0; i < 4; i++)
            #pragma unroll
            for (int j = 0; j < 4; j++) {
                acc[i][j] = __builtin_amdgcn_mfma_f32_16x16x32_bf16(ah[i], bh[j], acc[i][j], 0, 0, 0);
                acc[i][j] = __builtin_amdgcn_mfma_f32_16x16x32_bf16(ah[i], bl[j], acc[i][j], 0, 0, 0);
                acc[i][j] = __builtin_amdgcn_mfma_f32_16x16x32_bf16(al[i], bh[j], acc[i][j], 0, 0, 0);
            }
    }

    // ---- epilogue: C row = quad*4+reg (m), col = lane&15 (n) ----
    #pragma unroll
    for (int j = 0; j < 4; j++) {
        int n = n0 + nhalf * 64 + j * 16 + col;
        if (n < NUM_ENT) {
            float bv = be[n];
            #pragma unroll
            for (int i = 0; i < 4; i++) {
                int mbase = m0 + mq * 64 + i * 16 + quad * 4;
                #pragma unroll
                for (int r = 0; r < 4; r++)
                    out[(size_t)(mbase + r) * NUM_ENT + n] = sigf(acc[i][j][r] + bv);
            }
        }
    }
}

extern "C" void kernel_launch(void* const* d_in, const int* in_sizes, int n_in,
                              void* d_out, int out_size, void* d_ws, size_t ws_size,
                              hipStream_t stream) {
    const int*   e1  = (const int*)d_in[0];
    const int*   rel = (const int*)d_in[1];
    const float* emb = (const float*)d_in[2];
    const float* cw  = (const float*)d_in[3];
    const float* cb  = (const float*)d_in[4];
    const float* g0  = (const float*)d_in[5];
    const float* b0  = (const float*)d_in[6];
    const float* g1  = (const float*)d_in[7];
    const float* b1  = (const float*)d_in[8];
    const float* g2  = (const float*)d_in[9];
    const float* b2  = (const float*)d_in[10];
    const float* fcw = (const float*)d_in[11];
    const float* fcb = (const float*)d_in[12];
    const float* be  = (const float*)d_in[13];
    float* ws  = (float*)d_ws;
    float* out = (float*)d_out;

    k1a_bn0<<<64, 256, 0, stream>>>(e1, emb, ws);
    k1b_bn0<<<1, 64, 0, stream>>>(g0, ws);
    k2_conv<<<BATCH, 256, 0, stream>>>(e1, rel, emb, cw, cb, b0, ws);
    k3a_bn1<<<256, 256, 0, stream>>>(ws);
    k3b_bn1<<<1, 256, 0, stream>>>(g1, b1, ws);
    k4_fc  <<<dim3(4, 8, KSPLIT), 256, 0, stream>>>(ws, fcw);
    k5_bn2 <<<KPAD, 256, 0, stream>>>(g2, b2, fcb, ws);
    k6_gemm<<<782 * 2, 512, 0, stream>>>(ws, emb, be, out);
}

// Round 2
// 517.490 us; speedup vs baseline: 1.3436x; 1.2109x over previous
//
#include <hip/hip_runtime.h>
#include <hip/hip_bf16.h>

// ---------------- problem constants ----------------
#define BATCH   512
#define NUM_ENT 100000
#define EDIM    200
#define KPAD    224         // EDIM padded to multiple of 32
#define OCH     32          // conv out channels
#define OH      8
#define OW      18
#define FCK     4608        // 32*8*18
#define EPSV    1e-5f
#define KSPLIT  4           // k4 K-split factor (K chunk = 1152)

// ---------------- ws layout (float offsets) ----------------
#define WS0   0        // [2]    bn0: mean, rs*g0
#define BN1   8        // [64]   bn1: scale[32], shift[32]
#define K1P   512      // [128]  bn0 per-block partials
#define K3P   704      // [512]  bn1 per-block partials (256 blocks x {sum,sumsq})
#define YCOFF 2048     // [512*32*8*18] = 2359296 -> ends 2361344
#define PART  2361344  // [KSPLIT*512*200] = 409600 -> ends 2770944 (11.08 MB)
// A hi/lo (bf16) overlap the yc region (yc dead after k4):
#define AHI   2048     // 512*224 ushorts = 57344 floats -> ends 59392
#define ALO   59392    // 512*224 ushorts -> ends 116736 (< PART, no overlap)

typedef short bf16x8 __attribute__((ext_vector_type(8)));
typedef float f32x4  __attribute__((ext_vector_type(4)));

__device__ __forceinline__ float sigf(float x) {
    return 1.0f / (1.0f + __expf(-x));
}

__device__ __forceinline__ unsigned short bf16_rn(float v) {
    unsigned int u = __float_as_uint(v);
    unsigned int r = (u + 0x7FFFu + ((u >> 16) & 1u)) >> 16;
    return (unsigned short)r;
}

__device__ __forceinline__ void split_bf16(float v, unsigned short& hi, unsigned short& lo) {
    hi = bf16_rn(v);
    float hf = __uint_as_float(((unsigned int)hi) << 16);
    lo = bf16_rn(v - hf);
}

// k1a: bn0 partial sums over gathered embeddings
__global__ __launch_bounds__(256) void k1a_bn0(const int* __restrict__ e1,
                                               const float* __restrict__ emb,
                                               float* __restrict__ ws) {
    __shared__ float red[256], red2[256];
    int tid = threadIdx.x;
    int base = blockIdx.x * 1600;
    float s = 0.f, s2 = 0.f;
    for (int i = base + tid; i < base + 1600; i += 256) {
        int b = i / EDIM;
        int k = i - b * EDIM;
        float v = emb[(size_t)e1[b] * EDIM + k];
        s += v; s2 += v * v;
    }
    red[tid] = s; red2[tid] = s2;
    __syncthreads();
    for (int off = 128; off; off >>= 1) {
        if (tid < off) { red[tid] += red[tid + off]; red2[tid] += red2[tid + off]; }
        __syncthreads();
    }
    if (tid == 0) {
        ws[K1P + 2 * blockIdx.x + 0] = red[0];
        ws[K1P + 2 * blockIdx.x + 1] = red2[0];
    }
}

// k1b: finalize bn0
__global__ __launch_bounds__(64) void k1b_bn0(const float* __restrict__ g0,
                                              float* __restrict__ ws) {
    __shared__ float red[64], red2[64];
    int tid = threadIdx.x;
    red[tid]  = ws[K1P + 2 * tid + 0];
    red2[tid] = ws[K1P + 2 * tid + 1];
    __syncthreads();
    for (int off = 32; off; off >>= 1) {
        if (tid < off) { red[tid] += red[tid + off]; red2[tid] += red2[tid + off]; }
        __syncthreads();
    }
    if (tid == 0) {
        const float inv = 1.0f / (BATCH * EDIM);
        float m = red[0] * inv;
        float var = red2[0] * inv - m * m;
        ws[WS0 + 0] = m;
        ws[WS0 + 1] = rsqrtf(var + EPSV) * g0[0];
    }
}

// k2: relation-indexed 3x3 conv on bn0-normalized x
__global__ __launch_bounds__(256) void k2_conv(const int* __restrict__ e1,
                                               const int* __restrict__ rel,
                                               const float* __restrict__ emb,
                                               const float* __restrict__ cw,
                                               const float* __restrict__ cb,
                                               const float* __restrict__ b0,
                                               float* __restrict__ ws) {
    __shared__ float xs[EDIM];
    __shared__ float wsh[OCH * 9];
    __shared__ float bsh[OCH];
    int b = blockIdx.x, tid = threadIdx.x;
    float m = ws[WS0 + 0], s = ws[WS0 + 1], b0v = b0[0];
    int r = rel[b];
    if (tid < EDIM) xs[tid] = fmaf(emb[(size_t)e1[b] * EDIM + tid] - m, s, b0v);
    for (int i = tid; i < OCH * 9; i += 256) wsh[i] = cw[(size_t)r * OCH * 9 + i];
    if (tid < OCH) bsh[tid] = cb[r * OCH + tid];
    __syncthreads();
    int o = tid >> 3, h = tid & 7;
    float w0 = wsh[o*9+0], w1 = wsh[o*9+1], w2 = wsh[o*9+2];
    float w3 = wsh[o*9+3], w4 = wsh[o*9+4], w5 = wsh[o*9+5];
    float w6 = wsh[o*9+6], w7 = wsh[o*9+7], w8 = wsh[o*9+8];
    float bias = bsh[o];
    float* yout = ws + YCOFF + ((size_t)b * OCH + o) * (OH * OW) + h * OW;
    const float* r0 = &xs[(h + 0) * 20];
    const float* r1 = &xs[(h + 1) * 20];
    const float* r2 = &xs[(h + 2) * 20];
    #pragma unroll
    for (int wd = 0; wd < OW; wd++) {
        float acc = bias;
        acc = fmaf(r0[wd+0], w0, acc); acc = fmaf(r0[wd+1], w1, acc); acc = fmaf(r0[wd+2], w2, acc);
        acc = fmaf(r1[wd+0], w3, acc); acc = fmaf(r1[wd+1], w4, acc); acc = fmaf(r1[wd+2], w5, acc);
        acc = fmaf(r2[wd+0], w6, acc); acc = fmaf(r2[wd+1], w7, acc); acc = fmaf(r2[wd+2], w8, acc);
        yout[wd] = acc;
    }
}

// k3a: bn1 partial stats — 8 slices per channel, 256 blocks
__global__ __launch_bounds__(256) void k3a_bn1(float* __restrict__ ws) {
    __shared__ float red[256], red2[256];
    int o = blockIdx.x >> 3, sl = blockIdx.x & 7;
    int tid = threadIdx.x;
    const float* yc = ws + YCOFF;
    const int per = (BATCH * OH * OW) / 8;   // 9216
    float s = 0.f, s2 = 0.f;
    for (int i = sl * per + tid; i < (sl + 1) * per; i += 256) {
        int b = i / (OH * OW);
        int p = i - b * (OH * OW);
        float v = yc[((size_t)b * OCH + o) * (OH * OW) + p];
        s += v; s2 += v * v;
    }
    red[tid] = s; red2[tid] = s2;
    __syncthreads();
    for (int off = 128; off; off >>= 1) {
        if (tid < off) { red[tid] += red[tid + off]; red2[tid] += red2[tid + off]; }
        __syncthreads();
    }
    if (tid == 0) {
        ws[K3P + 2 * blockIdx.x + 0] = red[0];
        ws[K3P + 2 * blockIdx.x + 1] = red2[0];
    }
}

// k3b: finalize bn1 -> scale/shift
__global__ __launch_bounds__(256) void k3b_bn1(const float* __restrict__ g1,
                                               const float* __restrict__ b1,
                                               float* __restrict__ ws) {
    __shared__ float rs[256], rq[256];
    int tid = threadIdx.x;
    rs[tid] = ws[K3P + 2 * tid + 0];
    rq[tid] = ws[K3P + 2 * tid + 1];
    __syncthreads();
    if (tid < OCH) {
        float sm = 0.f, sq = 0.f;
        #pragma unroll
        for (int sl = 0; sl < 8; sl++) { sm += rs[tid * 8 + sl]; sq += rq[tid * 8 + sl]; }
        const float inv = 1.0f / (BATCH * OH * OW);
        float m = sm * inv;
        float var = sq * inv - m * m;
        float a = rsqrtf(var + EPSV) * g1[tid];
        ws[BN1 + tid] = a;
        ws[BN1 + 32 + tid] = b1[tid] - m * a;
    }
}

// k4: FC GEMM partials (fp32, K-split) — RESTRUCTURED for occupancy/latency:
//  - tile 32m x 32n, grid (7 n, 16 m, 4 ksplit) = 448 blocks (was 128) -> 1.75 blk/CU
//  - K-chunk 64 (was 16) -> 18 barrier iterations (was 72)
//  - float4 staging loads; LDS row stride 34 (8B-aligned float2 reads, no conflicts)
//  - inner k ascends identically to previous version -> PART bit-identical
__global__ __launch_bounds__(256) void k4_fc(float* __restrict__ ws,
                                             const float* __restrict__ fcw) {
    __shared__ float As[64][34];
    __shared__ float Bs[64][34];
    const float* yc = ws + YCOFF;
    const float* bn1p = ws + BN1;
    int tid = threadIdx.x;
    int tx = tid & 15, ty = tid >> 4;      // tx -> n pair, ty -> m pair
    int j0 = blockIdx.x * 32;              // 0..192 (covers 224 padded)
    int m0 = blockIdx.y * 32;
    int kbase = blockIdx.z * (FCK / KSPLIT);
    float* part = ws + PART + (size_t)blockIdx.z * BATCH * EDIM;
    float acc00 = 0.f, acc01 = 0.f, acc10 = 0.f, acc11 = 0.f;

    for (int kc = 0; kc < FCK / KSPLIT; kc += 64) {
        // stage A: 32 m x 64 k, bn1+relu applied; tasks = 32m x 16 kgroups(float4)
        for (int idx = tid; idx < 512; idx += 256) {
            int kg = idx & 15, mm = idx >> 4;
            int gk = kbase + kc + kg * 4;
            int o = gk / 144;                       // 4-group never straddles 144
            float sc = bn1p[o], sh = bn1p[32 + o];
            float4 v = *(const float4*)&yc[(size_t)(m0 + mm) * FCK + gk];
            float t0 = fmaf(v.x, sc, sh); t0 = t0 > 0.f ? t0 : 0.f;
            float t1 = fmaf(v.y, sc, sh); t1 = t1 > 0.f ? t1 : 0.f;
            float t2 = fmaf(v.z, sc, sh); t2 = t2 > 0.f ? t2 : 0.f;
            float t3 = fmaf(v.w, sc, sh); t3 = t3 > 0.f ? t3 : 0.f;
            As[kg * 4 + 0][mm] = t0;
            As[kg * 4 + 1][mm] = t1;
            As[kg * 4 + 2][mm] = t2;
            As[kg * 4 + 3][mm] = t3;
        }
        // stage B: 32 j x 64 k from fcw (zero-fill j >= EDIM)
        for (int idx = tid; idx < 512; idx += 256) {
            int kg = idx & 15, jj = idx >> 4;
            int gj = j0 + jj;
            float4 v = {0.f, 0.f, 0.f, 0.f};
            if (gj < EDIM)
                v = *(const float4*)&fcw[(size_t)gj * FCK + kbase + kc + kg * 4];
            Bs[kg * 4 + 0][jj] = v.x;
            Bs[kg * 4 + 1][jj] = v.y;
            Bs[kg * 4 + 2][jj] = v.z;
            Bs[kg * 4 + 3][jj] = v.w;
        }
        __syncthreads();
        #pragma unroll
        for (int kk = 0; kk < 64; kk++) {
            float2 a = *(const float2*)&As[kk][ty * 2];
            float2 b = *(const float2*)&Bs[kk][tx * 2];
            acc00 = fmaf(a.x, b.x, acc00);
            acc01 = fmaf(a.x, b.y, acc01);
            acc10 = fmaf(a.y, b.x, acc10);
            acc11 = fmaf(a.y, b.y, acc11);
        }
        __syncthreads();
    }
    {
        int m = m0 + ty * 2;
        int gj = j0 + tx * 2;
        if (gj + 0 < EDIM) part[(m + 0) * EDIM + gj + 0] = acc00;
        if (gj + 1 < EDIM) part[(m + 0) * EDIM + gj + 1] = acc01;
        if (gj + 0 < EDIM) part[(m + 1) * EDIM + gj + 0] = acc10;
        if (gj + 1 < EDIM) part[(m + 1) * EDIM + gj + 1] = acc11;
    }
}

// k5: y2 = sum_z part + fc_b; bn2; A = relu(bn2(y2)) split to bf16 hi/lo [512][224]
__global__ __launch_bounds__(256) void k5_bn2(const float* __restrict__ g2,
                                              const float* __restrict__ b2,
                                              const float* __restrict__ fcb,
                                              float* __restrict__ ws) {
    unsigned short* gAh = (unsigned short*)(ws + AHI);
    unsigned short* gAl = (unsigned short*)(ws + ALO);
    int j = blockIdx.x, tid = threadIdx.x;
    if (j >= EDIM) {   // zero padding columns 200..223
        for (int b = tid; b < BATCH; b += 256) {
            gAh[(size_t)b * KPAD + j] = 0;
            gAl[(size_t)b * KPAD + j] = 0;
        }
        return;
    }
    __shared__ float red[256], red2[256];
    __shared__ float ss[2];
    const float* part = ws + PART;
    float bias = fcb[j];
    float v0 = bias, v1 = bias;
    #pragma unroll
    for (int z = 0; z < KSPLIT; z++) {
        v0 += part[(size_t)z * BATCH * EDIM + tid * EDIM + j];
        v1 += part[(size_t)z * BATCH * EDIM + (tid + 256) * EDIM + j];
    }
    red[tid] = v0 + v1; red2[tid] = v0 * v0 + v1 * v1;
    __syncthreads();
    for (int off = 128; off; off >>= 1) {
        if (tid < off) { red[tid] += red[tid + off]; red2[tid] += red2[tid + off]; }
        __syncthreads();
    }
    if (tid == 0) {
        const float inv = 1.0f / BATCH;
        float m = red[0] * inv;
        float var = red2[0] * inv - m * m;
        float a = rsqrtf(var + EPSV) * g2[j];
        ss[0] = a;
        ss[1] = b2[j] - m * a;
    }
    __syncthreads();
    float a = ss[0], s = ss[1];
    float r0 = fmaf(v0, a, s); r0 = r0 > 0.f ? r0 : 0.f;
    float r1 = fmaf(v1, a, s); r1 = r1 > 0.f ? r1 : 0.f;
    unsigned short h, l;
    split_bf16(r0, h, l);
    gAh[(size_t)tid * KPAD + j] = h;  gAl[(size_t)tid * KPAD + j] = l;
    split_bf16(r1, h, l);
    gAh[(size_t)(tid + 256) * KPAD + j] = h;  gAl[(size_t)(tid + 256) * KPAD + j] = l;
}

// k6: logits = sigmoid( A @ emb^T + bias_e ), split-bf16 3-pass MFMA.
// ONE barrier per block, zero barriers in the K-loop.
//  - block tile = 128 ents (n) x 256 batch rows (m); grid 782*2 = 1564, 512 thr / 8 waves
//  - full B-tile (128 x 224 k) staged to LDS ONCE as split bf16 hi/lo in frag-order
//  - A hi/lo fragments loaded per-lane DIRECTLY from global (A = 458 KB, L2-resident)
//  - bijective XCD-chunked swizzle (1564 = 8*195+4)
__global__ __launch_bounds__(512, 2) void k6_gemm(const float* __restrict__ ws,
                                                  const float* __restrict__ emb,
                                                  const float* __restrict__ be,
                                                  float* __restrict__ out) {
    __shared__ unsigned short Bh[28672];   // 57344 B
    __shared__ unsigned short Bl[28672];   // 57344 B
    const unsigned short* gAh = (const unsigned short*)(ws + AHI);
    const unsigned short* gAl = (const unsigned short*)(ws + ALO);
    int tid = threadIdx.x;

    // XCD-chunked bijective swizzle (m204 formula): nwg=1564, q=195, r=4
    int orig = blockIdx.x;
    const int Q = 195, R = 4;
    int xcd = orig & 7, lin = orig >> 3;
    int wid = (xcd < R ? xcd * (Q + 1) : R * (Q + 1) + (xcd - R) * Q) + lin;
    int n0 = (wid >> 1) * 128;
    int m0 = (wid & 1) * 256;

    // ---- stage full B tile: 128 ents x 28 k-chunks of 8, fp32 -> split hi/lo ----
    for (int idx = tid; idx < 3584; idx += 512) {      // 3584 = 7 * 512, 7 iters
        int col = idx & 15;
        int t   = idx >> 4;          // g*28 + kch
        int g   = t / 28;
        int kch = t - g * 28;
        int rr  = g * 16 + col;
        int gn  = n0 + rr;
        float4 va = {0.f, 0.f, 0.f, 0.f};
        float4 vb = {0.f, 0.f, 0.f, 0.f};
        if (gn < NUM_ENT && kch < 25) {                // 25*8 = 200 = EDIM exactly
            const float* row = &emb[(size_t)gn * EDIM + kch * 8];
            va = *(const float4*)row;
            vb = *(const float4*)(row + 4);
        }
        unsigned short h0,h1,h2,h3,h4,h5,h6,h7, l0,l1,l2,l3,l4,l5,l6,l7;
        split_bf16(va.x, h0, l0); split_bf16(va.y, h1, l1);
        split_bf16(va.z, h2, l2); split_bf16(va.w, h3, l3);
        split_bf16(vb.x, h4, l4); split_bf16(vb.y, h5, l5);
        split_bf16(vb.z, h6, l6); split_bf16(vb.w, h7, l7);
        uint4 uh, ul;
        uh.x = (unsigned)h0 | ((unsigned)h1 << 16);
        uh.y = (unsigned)h2 | ((unsigned)h3 << 16);
        uh.z = (unsigned)h4 | ((unsigned)h5 << 16);
        uh.w = (unsigned)h6 | ((unsigned)h7 << 16);
        ul.x = (unsigned)l0 | ((unsigned)l1 << 16);
        ul.y = (unsigned)l2 | ((unsigned)l3 << 16);
        ul.z = (unsigned)l4 | ((unsigned)l5 << 16);
        ul.w = (unsigned)l6 | ((unsigned)l7 << 16);
        *(uint4*)&Bh[idx * 8] = uh;
        *(uint4*)&Bl[idx * 8] = ul;
    }
    __syncthreads();                                   // the ONLY barrier

    // ---- compute: wave = (mq in [0,4)) x (nhalf in [0,2)); 64m x 64n per wave ----
    int lane = tid & 63, col = lane & 15, quad = lane >> 4;
    int wave = tid >> 6;
    int nhalf = wave & 1, mq = wave >> 1;

    f32x4 acc[4][4];
    #pragma unroll
    for (int i = 0; i < 4; i++)
        #pragma unroll
        for (int j = 0; j < 4; j++)
            acc[i][j] = (f32x4){0.f, 0.f, 0.f, 0.f};

    int arow = m0 + mq * 64 + col;
    int gbase = nhalf * 4;

    for (int kc = 0; kc < KPAD; kc += 32) {            // 7 iters, no barriers
        bf16x8 ah[4], al[4], bh[4], bl[4];
        #pragma unroll
        for (int i = 0; i < 4; i++) {
            size_t aoff = (size_t)(arow + i * 16) * KPAD + kc + quad * 8;
            ah[i] = *(const bf16x8*)&gAh[aoff];
            al[i] = *(const bf16x8*)&gAl[aoff];
        }
        #pragma unroll
        for (int j = 0; j < 4; j++) {
            int boff = (((gbase + j) * 28) + (kc >> 3) + quad) * 128 + col * 8;
            bh[j] = *(const bf16x8*)&Bh[boff];
            bl[j] = *(const bf16x8*)&Bl[boff];
        }
        #pragma unroll
        for (int i = 0; i < 4; i++)
            #pragma unroll
            for (int j = 0; j < 4; j++) {
                acc[i][j] = __builtin_amdgcn_mfma_f32_16x16x32_bf16(ah[i], bh[j], acc[i][j], 0, 0, 0);
                acc[i][j] = __builtin_amdgcn_mfma_f32_16x16x32_bf16(ah[i], bl[j], acc[i][j], 0, 0, 0);
                acc[i][j] = __builtin_amdgcn_mfma_f32_16x16x32_bf16(al[i], bh[j], acc[i][j], 0, 0, 0);
            }
    }

    // ---- epilogue: C row = quad*4+reg (m), col = lane&15 (n) ----
    #pragma unroll
    for (int j = 0; j < 4; j++) {
        int n = n0 + nhalf * 64 + j * 16 + col;
        if (n < NUM_ENT) {
            float bv = be[n];
            #pragma unroll
            for (int i = 0; i < 4; i++) {
                int mbase = m0 + mq * 64 + i * 16 + quad * 4;
                #pragma unroll
                for (int r = 0; r < 4; r++)
                    out[(size_t)(mbase + r) * NUM_ENT + n] = sigf(acc[i][j][r] + bv);
            }
        }
    }
}

extern "C" void kernel_launch(void* const* d_in, const int* in_sizes, int n_in,
                              void* d_out, int out_size, void* d_ws, size_t ws_size,
                              hipStream_t stream) {
    const int*   e1  = (const int*)d_in[0];
    const int*   rel = (const int*)d_in[1];
    const float* emb = (const float*)d_in[2];
    const float* cw  = (const float*)d_in[3];
    const float* cb  = (const float*)d_in[4];
    const float* g0  = (const float*)d_in[5];
    const float* b0  = (const float*)d_in[6];
    const float* g1  = (const float*)d_in[7];
    const float* b1  = (const float*)d_in[8];
    const float* g2  = (const float*)d_in[9];
    const float* b2  = (const float*)d_in[10];
    const float* fcw = (const float*)d_in[11];
    const float* fcb = (const float*)d_in[12];
    const float* be  = (const float*)d_in[13];
    float* ws  = (float*)d_ws;
    float* out = (float*)d_out;

    k1a_bn0<<<64, 256, 0, stream>>>(e1, emb, ws);
    k1b_bn0<<<1, 64, 0, stream>>>(g0, ws);
    k2_conv<<<BATCH, 256, 0, stream>>>(e1, rel, emb, cw, cb, b0, ws);
    k3a_bn1<<<256, 256, 0, stream>>>(ws);
    k3b_bn1<<<1, 256, 0, stream>>>(g1, b1, ws);
    k4_fc  <<<dim3(7, 16, KSPLIT), 256, 0, stream>>>(ws, fcw);
    k5_bn2 <<<KPAD, 256, 0, stream>>>(g2, b2, fcb, ws);
    k6_gemm<<<782 * 2, 512, 0, stream>>>(ws, emb, be, out);
}

// Round 3
// 513.087 us; speedup vs baseline: 1.3551x; 1.0086x over previous
//
#include <hip/hip_runtime.h>
#include <hip/hip_bf16.h>

// ---------------- problem constants ----------------
#define BATCH   512
#define NUM_ENT 100000
#define EDIM    200
#define KPAD    224         // EDIM padded to multiple of 32
#define OCH     32          // conv out channels
#define OH      8
#define OW      18
#define FCK     4608        // 32*8*18
#define EPSV    1e-5f
#define KSPLIT  4           // k4 K-split factor (K chunk = 1152)

// ---------------- ws layout (float offsets) ----------------
#define WS0   0        // [2]    bn0: mean, rs*g0
#define BN1   8        // [64]   bn1: scale[32], shift[32]
#define K1P   512      // [128]  bn0 per-block partials
#define K3P   704      // [512]  bn1 per-block partials (256 blocks x {sum,sumsq})
#define YCOFF 2048     // [512*32*8*18] = 2359296 -> ends 2361344
#define PART  2361344  // [KSPLIT*512*200] = 409600 -> ends 2770944 (11.08 MB)
// A hi/lo (bf16) overlap the yc region (yc dead after k4):
#define AHI   2048     // 512*224 ushorts = 57344 floats -> ends 59392
#define ALO   59392    // 512*224 ushorts -> ends 116736 (< PART, no overlap)

typedef short bf16x8 __attribute__((ext_vector_type(8)));
typedef float f32x4  __attribute__((ext_vector_type(4)));

__device__ __forceinline__ float sigf(float x) {
    return 1.0f / (1.0f + __expf(-x));
}

__device__ __forceinline__ unsigned short bf16_rn(float v) {
    unsigned int u = __float_as_uint(v);
    unsigned int r = (u + 0x7FFFu + ((u >> 16) & 1u)) >> 16;
    return (unsigned short)r;
}

__device__ __forceinline__ void split_bf16(float v, unsigned short& hi, unsigned short& lo) {
    hi = bf16_rn(v);
    float hf = __uint_as_float(((unsigned int)hi) << 16);
    lo = bf16_rn(v - hf);
}

// k1a: bn0 partial sums over gathered embeddings
__global__ __launch_bounds__(256) void k1a_bn0(const int* __restrict__ e1,
                                               const float* __restrict__ emb,
                                               float* __restrict__ ws) {
    __shared__ float red[256], red2[256];
    int tid = threadIdx.x;
    int base = blockIdx.x * 1600;
    float s = 0.f, s2 = 0.f;
    for (int i = base + tid; i < base + 1600; i += 256) {
        int b = i / EDIM;
        int k = i - b * EDIM;
        float v = emb[(size_t)e1[b] * EDIM + k];
        s += v; s2 += v * v;
    }
    red[tid] = s; red2[tid] = s2;
    __syncthreads();
    for (int off = 128; off; off >>= 1) {
        if (tid < off) { red[tid] += red[tid + off]; red2[tid] += red2[tid + off]; }
        __syncthreads();
    }
    if (tid == 0) {
        ws[K1P + 2 * blockIdx.x + 0] = red[0];
        ws[K1P + 2 * blockIdx.x + 1] = red2[0];
    }
}

// k1b: finalize bn0
__global__ __launch_bounds__(64) void k1b_bn0(const float* __restrict__ g0,
                                              float* __restrict__ ws) {
    __shared__ float red[64], red2[64];
    int tid = threadIdx.x;
    red[tid]  = ws[K1P + 2 * tid + 0];
    red2[tid] = ws[K1P + 2 * tid + 1];
    __syncthreads();
    for (int off = 32; off; off >>= 1) {
        if (tid < off) { red[tid] += red[tid + off]; red2[tid] += red2[tid + off]; }
        __syncthreads();
    }
    if (tid == 0) {
        const float inv = 1.0f / (BATCH * EDIM);
        float m = red[0] * inv;
        float var = red2[0] * inv - m * m;
        ws[WS0 + 0] = m;
        ws[WS0 + 1] = rsqrtf(var + EPSV) * g0[0];
    }
}

// k2: relation-indexed 3x3 conv on bn0-normalized x
__global__ __launch_bounds__(256) void k2_conv(const int* __restrict__ e1,
                                               const int* __restrict__ rel,
                                               const float* __restrict__ emb,
                                               const float* __restrict__ cw,
                                               const float* __restrict__ cb,
                                               const float* __restrict__ b0,
                                               float* __restrict__ ws) {
    __shared__ float xs[EDIM];
    __shared__ float wsh[OCH * 9];
    __shared__ float bsh[OCH];
    int b = blockIdx.x, tid = threadIdx.x;
    float m = ws[WS0 + 0], s = ws[WS0 + 1], b0v = b0[0];
    int r = rel[b];
    if (tid < EDIM) xs[tid] = fmaf(emb[(size_t)e1[b] * EDIM + tid] - m, s, b0v);
    for (int i = tid; i < OCH * 9; i += 256) wsh[i] = cw[(size_t)r * OCH * 9 + i];
    if (tid < OCH) bsh[tid] = cb[r * OCH + tid];
    __syncthreads();
    int o = tid >> 3, h = tid & 7;
    float w0 = wsh[o*9+0], w1 = wsh[o*9+1], w2 = wsh[o*9+2];
    float w3 = wsh[o*9+3], w4 = wsh[o*9+4], w5 = wsh[o*9+5];
    float w6 = wsh[o*9+6], w7 = wsh[o*9+7], w8 = wsh[o*9+8];
    float bias = bsh[o];
    float* yout = ws + YCOFF + ((size_t)b * OCH + o) * (OH * OW) + h * OW;
    const float* r0 = &xs[(h + 0) * 20];
    const float* r1 = &xs[(h + 1) * 20];
    const float* r2 = &xs[(h + 2) * 20];
    #pragma unroll
    for (int wd = 0; wd < OW; wd++) {
        float acc = bias;
        acc = fmaf(r0[wd+0], w0, acc); acc = fmaf(r0[wd+1], w1, acc); acc = fmaf(r0[wd+2], w2, acc);
        acc = fmaf(r1[wd+0], w3, acc); acc = fmaf(r1[wd+1], w4, acc); acc = fmaf(r1[wd+2], w5, acc);
        acc = fmaf(r2[wd+0], w6, acc); acc = fmaf(r2[wd+1], w7, acc); acc = fmaf(r2[wd+2], w8, acc);
        yout[wd] = acc;
    }
}

// k3a: bn1 partial stats — 8 slices per channel, 256 blocks
__global__ __launch_bounds__(256) void k3a_bn1(float* __restrict__ ws) {
    __shared__ float red[256], red2[256];
    int o = blockIdx.x >> 3, sl = blockIdx.x & 7;
    int tid = threadIdx.x;
    const float* yc = ws + YCOFF;
    const int per = (BATCH * OH * OW) / 8;   // 9216
    float s = 0.f, s2 = 0.f;
    for (int i = sl * per + tid; i < (sl + 1) * per; i += 256) {
        int b = i / (OH * OW);
        int p = i - b * (OH * OW);
        float v = yc[((size_t)b * OCH + o) * (OH * OW) + p];
        s += v; s2 += v * v;
    }
    red[tid] = s; red2[tid] = s2;
    __syncthreads();
    for (int off = 128; off; off >>= 1) {
        if (tid < off) { red[tid] += red[tid + off]; red2[tid] += red2[tid + off]; }
        __syncthreads();
    }
    if (tid == 0) {
        ws[K3P + 2 * blockIdx.x + 0] = red[0];
        ws[K3P + 2 * blockIdx.x + 1] = red2[0];
    }
}

// k3b: finalize bn1 -> scale/shift
__global__ __launch_bounds__(256) void k3b_bn1(const float* __restrict__ g1,
                                               const float* __restrict__ b1,
                                               float* __restrict__ ws) {
    __shared__ float rs[256], rq[256];
    int tid = threadIdx.x;
    rs[tid] = ws[K3P + 2 * tid + 0];
    rq[tid] = ws[K3P + 2 * tid + 1];
    __syncthreads();
    if (tid < OCH) {
        float sm = 0.f, sq = 0.f;
        #pragma unroll
        for (int sl = 0; sl < 8; sl++) { sm += rs[tid * 8 + sl]; sq += rq[tid * 8 + sl]; }
        const float inv = 1.0f / (BATCH * OH * OW);
        float m = sm * inv;
        float var = sq * inv - m * m;
        float a = rsqrtf(var + EPSV) * g1[tid];
        ws[BN1 + tid] = a;
        ws[BN1 + 32 + tid] = b1[tid] - m * a;
    }
}

// k4: FC GEMM partials (fp32, K-split): 32x32 tile, 448 blocks, K-chunk 64
__global__ __launch_bounds__(256) void k4_fc(float* __restrict__ ws,
                                             const float* __restrict__ fcw) {
    __shared__ float As[64][34];
    __shared__ float Bs[64][34];
    const float* yc = ws + YCOFF;
    const float* bn1p = ws + BN1;
    int tid = threadIdx.x;
    int tx = tid & 15, ty = tid >> 4;      // tx -> n pair, ty -> m pair
    int j0 = blockIdx.x * 32;              // 0..192 (covers 224 padded)
    int m0 = blockIdx.y * 32;
    int kbase = blockIdx.z * (FCK / KSPLIT);
    float* part = ws + PART + (size_t)blockIdx.z * BATCH * EDIM;
    float acc00 = 0.f, acc01 = 0.f, acc10 = 0.f, acc11 = 0.f;

    for (int kc = 0; kc < FCK / KSPLIT; kc += 64) {
        // stage A: 32 m x 64 k, bn1+relu applied; tasks = 32m x 16 kgroups(float4)
        for (int idx = tid; idx < 512; idx += 256) {
            int kg = idx & 15, mm = idx >> 4;
            int gk = kbase + kc + kg * 4;
            int o = gk / 144;                       // 4-group never straddles 144
            float sc = bn1p[o], sh = bn1p[32 + o];
            float4 v = *(const float4*)&yc[(size_t)(m0 + mm) * FCK + gk];
            float t0 = fmaf(v.x, sc, sh); t0 = t0 > 0.f ? t0 : 0.f;
            float t1 = fmaf(v.y, sc, sh); t1 = t1 > 0.f ? t1 : 0.f;
            float t2 = fmaf(v.z, sc, sh); t2 = t2 > 0.f ? t2 : 0.f;
            float t3 = fmaf(v.w, sc, sh); t3 = t3 > 0.f ? t3 : 0.f;
            As[kg * 4 + 0][mm] = t0;
            As[kg * 4 + 1][mm] = t1;
            As[kg * 4 + 2][mm] = t2;
            As[kg * 4 + 3][mm] = t3;
        }
        // stage B: 32 j x 64 k from fcw (zero-fill j >= EDIM)
        for (int idx = tid; idx < 512; idx += 256) {
            int kg = idx & 15, jj = idx >> 4;
            int gj = j0 + jj;
            float4 v = {0.f, 0.f, 0.f, 0.f};
            if (gj < EDIM)
                v = *(const float4*)&fcw[(size_t)gj * FCK + kbase + kc + kg * 4];
            Bs[kg * 4 + 0][jj] = v.x;
            Bs[kg * 4 + 1][jj] = v.y;
            Bs[kg * 4 + 2][jj] = v.z;
            Bs[kg * 4 + 3][jj] = v.w;
        }
        __syncthreads();
        #pragma unroll
        for (int kk = 0; kk < 64; kk++) {
            float2 a = *(const float2*)&As[kk][ty * 2];
            float2 b = *(const float2*)&Bs[kk][tx * 2];
            acc00 = fmaf(a.x, b.x, acc00);
            acc01 = fmaf(a.x, b.y, acc01);
            acc10 = fmaf(a.y, b.x, acc10);
            acc11 = fmaf(a.y, b.y, acc11);
        }
        __syncthreads();
    }
    {
        int m = m0 + ty * 2;
        int gj = j0 + tx * 2;
        if (gj + 0 < EDIM) part[(m + 0) * EDIM + gj + 0] = acc00;
        if (gj + 1 < EDIM) part[(m + 0) * EDIM + gj + 1] = acc01;
        if (gj + 0 < EDIM) part[(m + 1) * EDIM + gj + 0] = acc10;
        if (gj + 1 < EDIM) part[(m + 1) * EDIM + gj + 1] = acc11;
    }
}

// k5: y2 = sum_z part + fc_b; bn2; A = relu(bn2(y2)) split to bf16 hi/lo [512][224]
__global__ __launch_bounds__(256) void k5_bn2(const float* __restrict__ g2,
                                              const float* __restrict__ b2,
                                              const float* __restrict__ fcb,
                                              float* __restrict__ ws) {
    unsigned short* gAh = (unsigned short*)(ws + AHI);
    unsigned short* gAl = (unsigned short*)(ws + ALO);
    int j = blockIdx.x, tid = threadIdx.x;
    if (j >= EDIM) {   // zero padding columns 200..223
        for (int b = tid; b < BATCH; b += 256) {
            gAh[(size_t)b * KPAD + j] = 0;
            gAl[(size_t)b * KPAD + j] = 0;
        }
        return;
    }
    __shared__ float red[256], red2[256];
    __shared__ float ss[2];
    const float* part = ws + PART;
    float bias = fcb[j];
    float v0 = bias, v1 = bias;
    #pragma unroll
    for (int z = 0; z < KSPLIT; z++) {
        v0 += part[(size_t)z * BATCH * EDIM + tid * EDIM + j];
        v1 += part[(size_t)z * BATCH * EDIM + (tid + 256) * EDIM + j];
    }
    red[tid] = v0 + v1; red2[tid] = v0 * v0 + v1 * v1;
    __syncthreads();
    for (int off = 128; off; off >>= 1) {
        if (tid < off) { red[tid] += red[tid + off]; red2[tid] += red2[tid + off]; }
        __syncthreads();
    }
    if (tid == 0) {
        const float inv = 1.0f / BATCH;
        float m = red[0] * inv;
        float var = red2[0] * inv - m * m;
        float a = rsqrtf(var + EPSV) * g2[j];
        ss[0] = a;
        ss[1] = b2[j] - m * a;
    }
    __syncthreads();
    float a = ss[0], s = ss[1];
    float r0 = fmaf(v0, a, s); r0 = r0 > 0.f ? r0 : 0.f;
    float r1 = fmaf(v1, a, s); r1 = r1 > 0.f ? r1 : 0.f;
    unsigned short h, l;
    split_bf16(r0, h, l);
    gAh[(size_t)tid * KPAD + j] = h;  gAl[(size_t)tid * KPAD + j] = l;
    split_bf16(r1, h, l);
    gAh[(size_t)(tid + 256) * KPAD + j] = h;  gAl[(size_t)(tid + 256) * KPAD + j] = l;
}

// k6: logits = sigmoid( A @ emb^T + bias_e ), split-bf16 3-pass MFMA.
// ONE barrier per block; K-loop fully unrolled with explicit 2-deep register
// double-buffer (named buffers, static indexing) so fragment loads for tile
// t+1 are in flight under the 48-MFMA cluster of tile t. This forces ~128
// fragment VGPRs live (total ~210) instead of the 88-VGPR register-minimal
// schedule that serialized per-fragment L2 latency.
__global__ __launch_bounds__(512, 2) void k6_gemm(const float* __restrict__ ws,
                                                  const float* __restrict__ emb,
                                                  const float* __restrict__ be,
                                                  float* __restrict__ out) {
    __shared__ unsigned short Bh[28672];   // 57344 B
    __shared__ unsigned short Bl[28672];   // 57344 B
    const unsigned short* gAh = (const unsigned short*)(ws + AHI);
    const unsigned short* gAl = (const unsigned short*)(ws + ALO);
    int tid = threadIdx.x;

    // XCD-chunked bijective swizzle (m204 formula): nwg=1564, q=195, r=4
    int orig = blockIdx.x;
    const int Q = 195, R = 4;
    int xcd = orig & 7, lin = orig >> 3;
    int wid = (xcd < R ? xcd * (Q + 1) : R * (Q + 1) + (xcd - R) * Q) + lin;
    int n0 = (wid >> 1) * 128;
    int m0 = (wid & 1) * 256;

    // ---- stage full B tile: 128 ents x 28 k-chunks of 8, fp32 -> split hi/lo ----
    // counted 7-trip loop, unrolled: all 14 emb float4 loads issue up front
    #pragma unroll
    for (int it = 0; it < 7; it++) {
        int idx = tid + it * 512;
        int col = idx & 15;
        int t   = idx >> 4;          // g*28 + kch
        int g   = t / 28;
        int kch = t - g * 28;
        int rr  = g * 16 + col;
        int gn  = n0 + rr;
        float4 va = {0.f, 0.f, 0.f, 0.f};
        float4 vb = {0.f, 0.f, 0.f, 0.f};
        if (gn < NUM_ENT && kch < 25) {                // 25*8 = 200 = EDIM exactly
            const float* row = &emb[(size_t)gn * EDIM + kch * 8];
            va = *(const float4*)row;
            vb = *(const float4*)(row + 4);
        }
        unsigned short h0,h1,h2,h3,h4,h5,h6,h7, l0,l1,l2,l3,l4,l5,l6,l7;
        split_bf16(va.x, h0, l0); split_bf16(va.y, h1, l1);
        split_bf16(va.z, h2, l2); split_bf16(va.w, h3, l3);
        split_bf16(vb.x, h4, l4); split_bf16(vb.y, h5, l5);
        split_bf16(vb.z, h6, l6); split_bf16(vb.w, h7, l7);
        uint4 uh, ul;
        uh.x = (unsigned)h0 | ((unsigned)h1 << 16);
        uh.y = (unsigned)h2 | ((unsigned)h3 << 16);
        uh.z = (unsigned)h4 | ((unsigned)h5 << 16);
        uh.w = (unsigned)h6 | ((unsigned)h7 << 16);
        ul.x = (unsigned)l0 | ((unsigned)l1 << 16);
        ul.y = (unsigned)l2 | ((unsigned)l3 << 16);
        ul.z = (unsigned)l4 | ((unsigned)l5 << 16);
        ul.w = (unsigned)l6 | ((unsigned)l7 << 16);
        *(uint4*)&Bh[idx * 8] = uh;
        *(uint4*)&Bl[idx * 8] = ul;
    }
    __syncthreads();                                   // the ONLY barrier

    // ---- compute: wave = (mq in [0,4)) x (nhalf in [0,2)); 64m x 64n per wave ----
    int lane = tid & 63, col = lane & 15, quad = lane >> 4;
    int wave = tid >> 6;
    int nhalf = wave & 1, mq = wave >> 1;

    f32x4 acc[4][4];
    #pragma unroll
    for (int i = 0; i < 4; i++)
        #pragma unroll
        for (int j = 0; j < 4; j++)
            acc[i][j] = (f32x4){0.f, 0.f, 0.f, 0.f};

    int arow = m0 + mq * 64 + col;
    int gbase = nhalf * 4;

    bf16x8 ah0[4], al0[4], bh0[4], bl0[4];
    bf16x8 ah1[4], al1[4], bh1[4], bl1[4];

#define K6_LOAD(T, AH, AL, BH, BL)                                             \
    {                                                                          \
        const int kc_ = (T) * 32;                                              \
        _Pragma("unroll")                                                      \
        for (int i = 0; i < 4; i++) {                                          \
            size_t aoff = (size_t)(arow + i * 16) * KPAD + kc_ + quad * 8;     \
            AH[i] = *(const bf16x8*)&gAh[aoff];                                \
            AL[i] = *(const bf16x8*)&gAl[aoff];                                \
        }                                                                      \
        _Pragma("unroll")                                                      \
        for (int j = 0; j < 4; j++) {                                          \
            int boff = (((gbase + j) * 28) + (kc_ >> 3) + quad) * 128 + col * 8; \
            BH[j] = *(const bf16x8*)&Bh[boff];                                 \
            BL[j] = *(const bf16x8*)&Bl[boff];                                 \
        }                                                                      \
    }

#define K6_MFMA(AH, AL, BH, BL)                                                \
    _Pragma("unroll")                                                          \
    for (int i = 0; i < 4; i++)                                                \
        _Pragma("unroll")                                                      \
        for (int j = 0; j < 4; j++) {                                          \
            acc[i][j] = __builtin_amdgcn_mfma_f32_16x16x32_bf16(AH[i], BH[j], acc[i][j], 0, 0, 0); \
            acc[i][j] = __builtin_amdgcn_mfma_f32_16x16x32_bf16(AH[i], BL[j], acc[i][j], 0, 0, 0); \
            acc[i][j] = __builtin_amdgcn_mfma_f32_16x16x32_bf16(AL[i], BH[j], acc[i][j], 0, 0, 0); \
        }

    // 7 K-tiles, 2-deep register double-buffer, accumulation order identical
    K6_LOAD(0, ah0, al0, bh0, bl0);
    K6_LOAD(1, ah1, al1, bh1, bl1);
    K6_MFMA(ah0, al0, bh0, bl0);        // tile 0
    K6_LOAD(2, ah0, al0, bh0, bl0);
    K6_MFMA(ah1, al1, bh1, bl1);        // tile 1
    K6_LOAD(3, ah1, al1, bh1, bl1);
    K6_MFMA(ah0, al0, bh0, bl0);        // tile 2
    K6_LOAD(4, ah0, al0, bh0, bl0);
    K6_MFMA(ah1, al1, bh1, bl1);        // tile 3
    K6_LOAD(5, ah1, al1, bh1, bl1);
    K6_MFMA(ah0, al0, bh0, bl0);        // tile 4
    K6_LOAD(6, ah0, al0, bh0, bl0);
    K6_MFMA(ah1, al1, bh1, bl1);        // tile 5
    K6_MFMA(ah0, al0, bh0, bl0);        // tile 6

#undef K6_LOAD
#undef K6_MFMA

    // ---- epilogue: C row = quad*4+reg (m), col = lane&15 (n) ----
    #pragma unroll
    for (int j = 0; j < 4; j++) {
        int n = n0 + nhalf * 64 + j * 16 + col;
        if (n < NUM_ENT) {
            float bv = be[n];
            #pragma unroll
            for (int i = 0; i < 4; i++) {
                int mbase = m0 + mq * 64 + i * 16 + quad * 4;
                #pragma unroll
                for (int r = 0; r < 4; r++)
                    out[(size_t)(mbase + r) * NUM_ENT + n] = sigf(acc[i][j][r] + bv);
            }
        }
    }
}

extern "C" void kernel_launch(void* const* d_in, const int* in_sizes, int n_in,
                              void* d_out, int out_size, void* d_ws, size_t ws_size,
                              hipStream_t stream) {
    const int*   e1  = (const int*)d_in[0];
    const int*   rel = (const int*)d_in[1];
    const float* emb = (const float*)d_in[2];
    const float* cw  = (const float*)d_in[3];
    const float* cb  = (const float*)d_in[4];
    const float* g0  = (const float*)d_in[5];
    const float* b0  = (const float*)d_in[6];
    const float* g1  = (const float*)d_in[7];
    const float* b1  = (const float*)d_in[8];
    const float* g2  = (const float*)d_in[9];
    const float* b2  = (const float*)d_in[10];
    const float* fcw = (const float*)d_in[11];
    const float* fcb = (const float*)d_in[12];
    const float* be  = (const float*)d_in[13];
    float* ws  = (float*)d_ws;
    float* out = (float*)d_out;

    k1a_bn0<<<64, 256, 0, stream>>>(e1, emb, ws);
    k1b_bn0<<<1, 64, 0, stream>>>(g0, ws);
    k2_conv<<<BATCH, 256, 0, stream>>>(e1, rel, emb, cw, cb, b0, ws);
    k3a_bn1<<<256, 256, 0, stream>>>(ws);
    k3b_bn1<<<1, 256, 0, stream>>>(g1, b1, ws);
    k4_fc  <<<dim3(7, 16, KSPLIT), 256, 0, stream>>>(ws, fcw);
    k5_bn2 <<<KPAD, 256, 0, stream>>>(g2, b2, fcb, ws);
    k6_gemm<<<782 * 2, 512, 0, stream>>>(ws, emb, be, out);
}

// Round 4
// 480.542 us; speedup vs baseline: 1.4469x; 1.0677x over previous
//
#include <hip/hip_runtime.h>
#include <hip/hip_bf16.h>

// ---------------- problem constants ----------------
#define BATCH   512
#define NUM_ENT 100000
#define EDIM    200
#define KPAD    224         // EDIM padded to multiple of 32
#define OCH     32          // conv out channels
#define OH      8
#define OW      18
#define FCK     4608        // 32*8*18
#define EPSV    1e-5f
#define KSPLIT  4           // k4 K-split factor (K chunk = 1152)

// ---------------- ws layout (float offsets) ----------------
#define WS0   0        // [2]    bn0: mean, rs*g0
#define BN1   8        // [64]   bn1: scale[32], shift[32]
#define K1P   512      // [128]  bn0 per-block partials
#define K3P   704      // [512]  bn1 per-block partials (256 blocks x {sum,sumsq})
#define YCOFF 2048     // [512*32*8*18] = 2359296 -> ends 2361344
#define PART  2361344  // [KSPLIT*512*200] = 409600 -> ends 2770944 (11.08 MB)
// A hi/lo (bf16) overlap the yc region (yc dead after k4):
#define AHI   2048     // 512*224 ushorts = 57344 floats -> ends 59392
#define ALO   59392    // 512*224 ushorts -> ends 116736 (< PART, no overlap)

typedef short bf16x8 __attribute__((ext_vector_type(8)));
typedef float f32x4  __attribute__((ext_vector_type(4)));

__device__ __forceinline__ float sigf(float x) {
    return 1.0f / (1.0f + __expf(-x));
}

__device__ __forceinline__ unsigned short bf16_rn(float v) {
    unsigned int u = __float_as_uint(v);
    unsigned int r = (u + 0x7FFFu + ((u >> 16) & 1u)) >> 16;
    return (unsigned short)r;
}

__device__ __forceinline__ void split_bf16(float v, unsigned short& hi, unsigned short& lo) {
    hi = bf16_rn(v);
    float hf = __uint_as_float(((unsigned int)hi) << 16);
    lo = bf16_rn(v - hf);
}

// k1a: bn0 partial sums over gathered embeddings
__global__ __launch_bounds__(256) void k1a_bn0(const int* __restrict__ e1,
                                               const float* __restrict__ emb,
                                               float* __restrict__ ws) {
    __shared__ float red[256], red2[256];
    int tid = threadIdx.x;
    int base = blockIdx.x * 1600;
    float s = 0.f, s2 = 0.f;
    for (int i = base + tid; i < base + 1600; i += 256) {
        int b = i / EDIM;
        int k = i - b * EDIM;
        float v = emb[(size_t)e1[b] * EDIM + k];
        s += v; s2 += v * v;
    }
    red[tid] = s; red2[tid] = s2;
    __syncthreads();
    for (int off = 128; off; off >>= 1) {
        if (tid < off) { red[tid] += red[tid + off]; red2[tid] += red2[tid + off]; }
        __syncthreads();
    }
    if (tid == 0) {
        ws[K1P + 2 * blockIdx.x + 0] = red[0];
        ws[K1P + 2 * blockIdx.x + 1] = red2[0];
    }
}

// k1b: finalize bn0
__global__ __launch_bounds__(64) void k1b_bn0(const float* __restrict__ g0,
                                              float* __restrict__ ws) {
    __shared__ float red[64], red2[64];
    int tid = threadIdx.x;
    red[tid]  = ws[K1P + 2 * tid + 0];
    red2[tid] = ws[K1P + 2 * tid + 1];
    __syncthreads();
    for (int off = 32; off; off >>= 1) {
        if (tid < off) { red[tid] += red[tid + off]; red2[tid] += red2[tid + off]; }
        __syncthreads();
    }
    if (tid == 0) {
        const float inv = 1.0f / (BATCH * EDIM);
        float m = red[0] * inv;
        float var = red2[0] * inv - m * m;
        ws[WS0 + 0] = m;
        ws[WS0 + 1] = rsqrtf(var + EPSV) * g0[0];
    }
}

// k2: relation-indexed 3x3 conv on bn0-normalized x
__global__ __launch_bounds__(256) void k2_conv(const int* __restrict__ e1,
                                               const int* __restrict__ rel,
                                               const float* __restrict__ emb,
                                               const float* __restrict__ cw,
                                               const float* __restrict__ cb,
                                               const float* __restrict__ b0,
                                               float* __restrict__ ws) {
    __shared__ float xs[EDIM];
    __shared__ float wsh[OCH * 9];
    __shared__ float bsh[OCH];
    int b = blockIdx.x, tid = threadIdx.x;
    float m = ws[WS0 + 0], s = ws[WS0 + 1], b0v = b0[0];
    int r = rel[b];
    if (tid < EDIM) xs[tid] = fmaf(emb[(size_t)e1[b] * EDIM + tid] - m, s, b0v);
    for (int i = tid; i < OCH * 9; i += 256) wsh[i] = cw[(size_t)r * OCH * 9 + i];
    if (tid < OCH) bsh[tid] = cb[r * OCH + tid];
    __syncthreads();
    int o = tid >> 3, h = tid & 7;
    float w0 = wsh[o*9+0], w1 = wsh[o*9+1], w2 = wsh[o*9+2];
    float w3 = wsh[o*9+3], w4 = wsh[o*9+4], w5 = wsh[o*9+5];
    float w6 = wsh[o*9+6], w7 = wsh[o*9+7], w8 = wsh[o*9+8];
    float bias = bsh[o];
    float* yout = ws + YCOFF + ((size_t)b * OCH + o) * (OH * OW) + h * OW;
    const float* r0 = &xs[(h + 0) * 20];
    const float* r1 = &xs[(h + 1) * 20];
    const float* r2 = &xs[(h + 2) * 20];
    #pragma unroll
    for (int wd = 0; wd < OW; wd++) {
        float acc = bias;
        acc = fmaf(r0[wd+0], w0, acc); acc = fmaf(r0[wd+1], w1, acc); acc = fmaf(r0[wd+2], w2, acc);
        acc = fmaf(r1[wd+0], w3, acc); acc = fmaf(r1[wd+1], w4, acc); acc = fmaf(r1[wd+2], w5, acc);
        acc = fmaf(r2[wd+0], w6, acc); acc = fmaf(r2[wd+1], w7, acc); acc = fmaf(r2[wd+2], w8, acc);
        yout[wd] = acc;
    }
}

// k3a: bn1 partial stats — 8 slices per channel, 256 blocks
__global__ __launch_bounds__(256) void k3a_bn1(float* __restrict__ ws) {
    __shared__ float red[256], red2[256];
    int o = blockIdx.x >> 3, sl = blockIdx.x & 7;
    int tid = threadIdx.x;
    const float* yc = ws + YCOFF;
    const int per = (BATCH * OH * OW) / 8;   // 9216
    float s = 0.f, s2 = 0.f;
    for (int i = sl * per + tid; i < (sl + 1) * per; i += 256) {
        int b = i / (OH * OW);
        int p = i - b * (OH * OW);
        float v = yc[((size_t)b * OCH + o) * (OH * OW) + p];
        s += v; s2 += v * v;
    }
    red[tid] = s; red2[tid] = s2;
    __syncthreads();
    for (int off = 128; off; off >>= 1) {
        if (tid < off) { red[tid] += red[tid + off]; red2[tid] += red2[tid + off]; }
        __syncthreads();
    }
    if (tid == 0) {
        ws[K3P + 2 * blockIdx.x + 0] = red[0];
        ws[K3P + 2 * blockIdx.x + 1] = red2[0];
    }
}

// k3b: finalize bn1 -> scale/shift
__global__ __launch_bounds__(256) void k3b_bn1(const float* __restrict__ g1,
                                               const float* __restrict__ b1,
                                               float* __restrict__ ws) {
    __shared__ float rs[256], rq[256];
    int tid = threadIdx.x;
    rs[tid] = ws[K3P + 2 * tid + 0];
    rq[tid] = ws[K3P + 2 * tid + 1];
    __syncthreads();
    if (tid < OCH) {
        float sm = 0.f, sq = 0.f;
        #pragma unroll
        for (int sl = 0; sl < 8; sl++) { sm += rs[tid * 8 + sl]; sq += rq[tid * 8 + sl]; }
        const float inv = 1.0f / (BATCH * OH * OW);
        float m = sm * inv;
        float var = sq * inv - m * m;
        float a = rsqrtf(var + EPSV) * g1[tid];
        ws[BN1 + tid] = a;
        ws[BN1 + 32 + tid] = b1[tid] - m * a;
    }
}

// k4: FC GEMM partials (fp32, K-split): 32x32 tile, 448 blocks, K-chunk 64
__global__ __launch_bounds__(256) void k4_fc(float* __restrict__ ws,
                                             const float* __restrict__ fcw) {
    __shared__ float As[64][34];
    __shared__ float Bs[64][34];
    const float* yc = ws + YCOFF;
    const float* bn1p = ws + BN1;
    int tid = threadIdx.x;
    int tx = tid & 15, ty = tid >> 4;      // tx -> n pair, ty -> m pair
    int j0 = blockIdx.x * 32;              // 0..192 (covers 224 padded)
    int m0 = blockIdx.y * 32;
    int kbase = blockIdx.z * (FCK / KSPLIT);
    float* part = ws + PART + (size_t)blockIdx.z * BATCH * EDIM;
    float acc00 = 0.f, acc01 = 0.f, acc10 = 0.f, acc11 = 0.f;

    for (int kc = 0; kc < FCK / KSPLIT; kc += 64) {
        // stage A: 32 m x 64 k, bn1+relu applied; tasks = 32m x 16 kgroups(float4)
        for (int idx = tid; idx < 512; idx += 256) {
            int kg = idx & 15, mm = idx >> 4;
            int gk = kbase + kc + kg * 4;
            int o = gk / 144;                       // 4-group never straddles 144
            float sc = bn1p[o], sh = bn1p[32 + o];
            float4 v = *(const float4*)&yc[(size_t)(m0 + mm) * FCK + gk];
            float t0 = fmaf(v.x, sc, sh); t0 = t0 > 0.f ? t0 : 0.f;
            float t1 = fmaf(v.y, sc, sh); t1 = t1 > 0.f ? t1 : 0.f;
            float t2 = fmaf(v.z, sc, sh); t2 = t2 > 0.f ? t2 : 0.f;
            float t3 = fmaf(v.w, sc, sh); t3 = t3 > 0.f ? t3 : 0.f;
            As[kg * 4 + 0][mm] = t0;
            As[kg * 4 + 1][mm] = t1;
            As[kg * 4 + 2][mm] = t2;
            As[kg * 4 + 3][mm] = t3;
        }
        // stage B: 32 j x 64 k from fcw (zero-fill j >= EDIM)
        for (int idx = tid; idx < 512; idx += 256) {
            int kg = idx & 15, jj = idx >> 4;
            int gj = j0 + jj;
            float4 v = {0.f, 0.f, 0.f, 0.f};
            if (gj < EDIM)
                v = *(const float4*)&fcw[(size_t)gj * FCK + kbase + kc + kg * 4];
            Bs[kg * 4 + 0][jj] = v.x;
            Bs[kg * 4 + 1][jj] = v.y;
            Bs[kg * 4 + 2][jj] = v.z;
            Bs[kg * 4 + 3][jj] = v.w;
        }
        __syncthreads();
        #pragma unroll
        for (int kk = 0; kk < 64; kk++) {
            float2 a = *(const float2*)&As[kk][ty * 2];
            float2 b = *(const float2*)&Bs[kk][tx * 2];
            acc00 = fmaf(a.x, b.x, acc00);
            acc01 = fmaf(a.x, b.y, acc01);
            acc10 = fmaf(a.y, b.x, acc10);
            acc11 = fmaf(a.y, b.y, acc11);
        }
        __syncthreads();
    }
    {
        int m = m0 + ty * 2;
        int gj = j0 + tx * 2;
        if (gj + 0 < EDIM) part[(m + 0) * EDIM + gj + 0] = acc00;
        if (gj + 1 < EDIM) part[(m + 0) * EDIM + gj + 1] = acc01;
        if (gj + 0 < EDIM) part[(m + 1) * EDIM + gj + 0] = acc10;
        if (gj + 1 < EDIM) part[(m + 1) * EDIM + gj + 1] = acc11;
    }
}

// k5: y2 = sum_z part + fc_b; bn2; A = relu(bn2(y2)) split to bf16 hi/lo [512][224]
__global__ __launch_bounds__(256) void k5_bn2(const float* __restrict__ g2,
                                              const float* __restrict__ b2,
                                              const float* __restrict__ fcb,
                                              float* __restrict__ ws) {
    unsigned short* gAh = (unsigned short*)(ws + AHI);
    unsigned short* gAl = (unsigned short*)(ws + ALO);
    int j = blockIdx.x, tid = threadIdx.x;
    if (j >= EDIM) {   // zero padding columns 200..223
        for (int b = tid; b < BATCH; b += 256) {
            gAh[(size_t)b * KPAD + j] = 0;
            gAl[(size_t)b * KPAD + j] = 0;
        }
        return;
    }
    __shared__ float red[256], red2[256];
    __shared__ float ss[2];
    const float* part = ws + PART;
    float bias = fcb[j];
    float v0 = bias, v1 = bias;
    #pragma unroll
    for (int z = 0; z < KSPLIT; z++) {
        v0 += part[(size_t)z * BATCH * EDIM + tid * EDIM + j];
        v1 += part[(size_t)z * BATCH * EDIM + (tid + 256) * EDIM + j];
    }
    red[tid] = v0 + v1; red2[tid] = v0 * v0 + v1 * v1;
    __syncthreads();
    for (int off = 128; off; off >>= 1) {
        if (tid < off) { red[tid] += red[tid + off]; red2[tid] += red2[tid + off]; }
        __syncthreads();
    }
    if (tid == 0) {
        const float inv = 1.0f / BATCH;
        float m = red[0] * inv;
        float var = red2[0] * inv - m * m;
        float a = rsqrtf(var + EPSV) * g2[j];
        ss[0] = a;
        ss[1] = b2[j] - m * a;
    }
    __syncthreads();
    float a = ss[0], s = ss[1];
    float r0 = fmaf(v0, a, s); r0 = r0 > 0.f ? r0 : 0.f;
    float r1 = fmaf(v1, a, s); r1 = r1 > 0.f ? r1 : 0.f;
    unsigned short h, l;
    split_bf16(r0, h, l);
    gAh[(size_t)tid * KPAD + j] = h;  gAl[(size_t)tid * KPAD + j] = l;
    split_bf16(r1, h, l);
    gAh[(size_t)(tid + 256) * KPAD + j] = h;  gAl[(size_t)(tid + 256) * KPAD + j] = l;
}

// k6: logits = sigmoid( A @ emb^T + bias_e ), split-bf16 3-pass MFMA.
// OCCUPANCY-FIRST redesign:
//  - block tile = 64 ents (n) x 512 batch rows (m, full batch)
//  - 1024 threads = 16 waves = 4 waves/SIMD (2x prev) ; wave tile 32m x 64n
//  - LDS halved to 57 KB (64 x 224 hi/lo, frag-order, contiguous-1KB wave reads)
//  - each emb element loaded+split exactly ONCE per kernel (n-tiles partition ents)
//  - A fragments per-lane from global (458 KB, L2-resident); one barrier total
//  - no XCD swizzle: no inter-block emb reuse anymore
// Per-output K accumulation chain identical (kc ascending; hh,hl,lh) -> bit-identical.
__global__ __launch_bounds__(1024) void k6_gemm(const float* __restrict__ ws,
                                                const float* __restrict__ emb,
                                                const float* __restrict__ be,
                                                float* __restrict__ out) {
    __shared__ unsigned short Bh[14336];   // 28672 B
    __shared__ unsigned short Bl[14336];   // 28672 B
    const unsigned short* gAh = (const unsigned short*)(ws + AHI);
    const unsigned short* gAl = (const unsigned short*)(ws + ALO);
    int tid = threadIdx.x;
    int n0 = blockIdx.x * 64;

    // ---- stage B tile: 64 ents x 28 k-chunks of 8, fp32 -> split hi/lo ----
    // slot = (g*28 + kch)*16 + col  (g = ent>>4, col = ent&15); 1792 slots x 16B
    for (int idx = tid; idx < 1792; idx += 1024) {
        int col = idx & 15;
        int t   = idx >> 4;          // g*28 + kch
        int g   = t / 28;
        int kch = t - g * 28;
        int gn  = n0 + g * 16 + col;
        float4 va = {0.f, 0.f, 0.f, 0.f};
        float4 vb = {0.f, 0.f, 0.f, 0.f};
        if (gn < NUM_ENT && kch < 25) {                // 25*8 = 200 = EDIM exactly
            const float* row = &emb[(size_t)gn * EDIM + kch * 8];
            va = *(const float4*)row;
            vb = *(const float4*)(row + 4);
        }
        unsigned short h0,h1,h2,h3,h4,h5,h6,h7, l0,l1,l2,l3,l4,l5,l6,l7;
        split_bf16(va.x, h0, l0); split_bf16(va.y, h1, l1);
        split_bf16(va.z, h2, l2); split_bf16(va.w, h3, l3);
        split_bf16(vb.x, h4, l4); split_bf16(vb.y, h5, l5);
        split_bf16(vb.z, h6, l6); split_bf16(vb.w, h7, l7);
        uint4 uh, ul;
        uh.x = (unsigned)h0 | ((unsigned)h1 << 16);
        uh.y = (unsigned)h2 | ((unsigned)h3 << 16);
        uh.z = (unsigned)h4 | ((unsigned)h5 << 16);
        uh.w = (unsigned)h6 | ((unsigned)h7 << 16);
        ul.x = (unsigned)l0 | ((unsigned)l1 << 16);
        ul.y = (unsigned)l2 | ((unsigned)l3 << 16);
        ul.z = (unsigned)l4 | ((unsigned)l5 << 16);
        ul.w = (unsigned)l6 | ((unsigned)l7 << 16);
        *(uint4*)&Bh[idx * 8] = uh;
        *(uint4*)&Bl[idx * 8] = ul;
    }
    __syncthreads();                                   // the ONLY barrier

    // ---- compute: wave mq in [0,16) -> rows mq*32..mq*32+31 ; all 64 n ----
    int lane = tid & 63, col = lane & 15, quad = lane >> 4;
    int mq = tid >> 6;

    f32x4 acc[2][4];
    #pragma unroll
    for (int i = 0; i < 2; i++)
        #pragma unroll
        for (int j = 0; j < 4; j++)
            acc[i][j] = (f32x4){0.f, 0.f, 0.f, 0.f};

    int arow = mq * 32 + col;

    for (int kc = 0; kc < KPAD; kc += 32) {            // 7 iters, no barriers
        bf16x8 ah[2], al[2], bh[4], bl[4];
        #pragma unroll
        for (int i = 0; i < 2; i++) {
            size_t aoff = (size_t)(arow + i * 16) * KPAD + kc + quad * 8;
            ah[i] = *(const bf16x8*)&gAh[aoff];
            al[i] = *(const bf16x8*)&gAl[aoff];
        }
        #pragma unroll
        for (int j = 0; j < 4; j++) {
            int boff = ((j * 28 + (kc >> 3) + quad) * 16 + col) * 8;
            bh[j] = *(const bf16x8*)&Bh[boff];
            bl[j] = *(const bf16x8*)&Bl[boff];
        }
        #pragma unroll
        for (int i = 0; i < 2; i++)
            #pragma unroll
            for (int j = 0; j < 4; j++) {
                acc[i][j] = __builtin_amdgcn_mfma_f32_16x16x32_bf16(ah[i], bh[j], acc[i][j], 0, 0, 0);
                acc[i][j] = __builtin_amdgcn_mfma_f32_16x16x32_bf16(ah[i], bl[j], acc[i][j], 0, 0, 0);
                acc[i][j] = __builtin_amdgcn_mfma_f32_16x16x32_bf16(al[i], bh[j], acc[i][j], 0, 0, 0);
            }
    }

    // ---- epilogue: C row = quad*4+reg (m), col = lane&15 (n) ----
    #pragma unroll
    for (int j = 0; j < 4; j++) {
        int n = n0 + j * 16 + col;
        if (n < NUM_ENT) {
            float bv = be[n];
            #pragma unroll
            for (int i = 0; i < 2; i++) {
                int mbase = mq * 32 + i * 16 + quad * 4;
                #pragma unroll
                for (int r = 0; r < 4; r++)
                    out[(size_t)(mbase + r) * NUM_ENT + n] = sigf(acc[i][j][r] + bv);
            }
        }
    }
}

extern "C" void kernel_launch(void* const* d_in, const int* in_sizes, int n_in,
                              void* d_out, int out_size, void* d_ws, size_t ws_size,
                              hipStream_t stream) {
    const int*   e1  = (const int*)d_in[0];
    const int*   rel = (const int*)d_in[1];
    const float* emb = (const float*)d_in[2];
    const float* cw  = (const float*)d_in[3];
    const float* cb  = (const float*)d_in[4];
    const float* g0  = (const float*)d_in[5];
    const float* b0  = (const float*)d_in[6];
    const float* g1  = (const float*)d_in[7];
    const float* b1  = (const float*)d_in[8];
    const float* g2  = (const float*)d_in[9];
    const float* b2  = (const float*)d_in[10];
    const float* fcw = (const float*)d_in[11];
    const float* fcb = (const float*)d_in[12];
    const float* be  = (const float*)d_in[13];
    float* ws  = (float*)d_ws;
    float* out = (float*)d_out;

    k1a_bn0<<<64, 256, 0, stream>>>(e1, emb, ws);
    k1b_bn0<<<1, 64, 0, stream>>>(g0, ws);
    k2_conv<<<BATCH, 256, 0, stream>>>(e1, rel, emb, cw, cb, b0, ws);
    k3a_bn1<<<256, 256, 0, stream>>>(ws);
    k3b_bn1<<<1, 256, 0, stream>>>(g1, b1, ws);
    k4_fc  <<<dim3(7, 16, KSPLIT), 256, 0, stream>>>(ws, fcw);
    k5_bn2 <<<KPAD, 256, 0, stream>>>(g2, b2, fcb, ws);
    k6_gemm<<<1563, 1024, 0, stream>>>(ws, emb, be, out);
}

// Round 6
// 449.446 us; speedup vs baseline: 1.5470x; 1.0692x over previous
//
#include <hip/hip_runtime.h>
#include <hip/hip_bf16.h>

// ---------------- problem constants ----------------
#define BATCH   512
#define NUM_ENT 100000
#define EDIM    200
#define KPAD    224         // EDIM padded to multiple of 32
#define OCH     32          // conv out channels
#define OH      8
#define OW      18
#define FCK     4608        // 32*8*18
#define EPSV    1e-5f
#define KSPLIT  4           // k4 K-split factor (K chunk = 1152)

// ---------------- ws layout (float offsets) ----------------
#define WS0   0        // [2]    bn0: mean, rs*g0
#define BN1   8        // [64]   bn1: scale[32], shift[32]
#define K1P   512      // [128]  bn0 per-block partials
#define K3P   704      // [512]  bn1 per-block partials (256 blocks x {sum,sumsq})
#define YCOFF 2048     // [512*32*8*18] = 2359296 -> ends 2361344
#define PART  2361344  // [KSPLIT*512*200] = 409600 -> ends 2770944 (11.08 MB)
// A hi/lo (bf16) overlap the yc region (yc dead after k4):
#define AHI   2048     // 512*224 ushorts = 57344 floats -> ends 59392
#define ALO   59392    // 512*224 ushorts -> ends 116736 (< PART, no overlap)

typedef short bf16x8 __attribute__((ext_vector_type(8)));
typedef float f32x4  __attribute__((ext_vector_type(4)));

__device__ __forceinline__ float sigf(float x) {
    return 1.0f / (1.0f + __expf(-x));
}

__device__ __forceinline__ unsigned short bf16_rn(float v) {
    unsigned int u = __float_as_uint(v);
    unsigned int r = (u + 0x7FFFu + ((u >> 16) & 1u)) >> 16;
    return (unsigned short)r;
}

__device__ __forceinline__ void split_bf16(float v, unsigned short& hi, unsigned short& lo) {
    hi = bf16_rn(v);
    float hf = __uint_as_float(((unsigned int)hi) << 16);
    lo = bf16_rn(v - hf);
}

// k1a: bn0 partial sums over gathered embeddings
__global__ __launch_bounds__(256) void k1a_bn0(const int* __restrict__ e1,
                                               const float* __restrict__ emb,
                                               float* __restrict__ ws) {
    __shared__ float red[256], red2[256];
    int tid = threadIdx.x;
    int base = blockIdx.x * 1600;
    float s = 0.f, s2 = 0.f;
    for (int i = base + tid; i < base + 1600; i += 256) {
        int b = i / EDIM;
        int k = i - b * EDIM;
        float v = emb[(size_t)e1[b] * EDIM + k];
        s += v; s2 += v * v;
    }
    red[tid] = s; red2[tid] = s2;
    __syncthreads();
    for (int off = 128; off; off >>= 1) {
        if (tid < off) { red[tid] += red[tid + off]; red2[tid] += red2[tid + off]; }
        __syncthreads();
    }
    if (tid == 0) {
        ws[K1P + 2 * blockIdx.x + 0] = red[0];
        ws[K1P + 2 * blockIdx.x + 1] = red2[0];
    }
}

// k1b: finalize bn0
__global__ __launch_bounds__(64) void k1b_bn0(const float* __restrict__ g0,
                                              float* __restrict__ ws) {
    __shared__ float red[64], red2[64];
    int tid = threadIdx.x;
    red[tid]  = ws[K1P + 2 * tid + 0];
    red2[tid] = ws[K1P + 2 * tid + 1];
    __syncthreads();
    for (int off = 32; off; off >>= 1) {
        if (tid < off) { red[tid] += red[tid + off]; red2[tid] += red2[tid + off]; }
        __syncthreads();
    }
    if (tid == 0) {
        const float inv = 1.0f / (BATCH * EDIM);
        float m = red[0] * inv;
        float var = red2[0] * inv - m * m;
        ws[WS0 + 0] = m;
        ws[WS0 + 1] = rsqrtf(var + EPSV) * g0[0];
    }
}

// k2: relation-indexed 3x3 conv on bn0-normalized x
__global__ __launch_bounds__(256) void k2_conv(const int* __restrict__ e1,
                                               const int* __restrict__ rel,
                                               const float* __restrict__ emb,
                                               const float* __restrict__ cw,
                                               const float* __restrict__ cb,
                                               const float* __restrict__ b0,
                                               float* __restrict__ ws) {
    __shared__ float xs[EDIM];
    __shared__ float wsh[OCH * 9];
    __shared__ float bsh[OCH];
    int b = blockIdx.x, tid = threadIdx.x;
    float m = ws[WS0 + 0], s = ws[WS0 + 1], b0v = b0[0];
    int r = rel[b];
    if (tid < EDIM) xs[tid] = fmaf(emb[(size_t)e1[b] * EDIM + tid] - m, s, b0v);
    for (int i = tid; i < OCH * 9; i += 256) wsh[i] = cw[(size_t)r * OCH * 9 + i];
    if (tid < OCH) bsh[tid] = cb[r * OCH + tid];
    __syncthreads();
    int o = tid >> 3, h = tid & 7;
    float w0 = wsh[o*9+0], w1 = wsh[o*9+1], w2 = wsh[o*9+2];
    float w3 = wsh[o*9+3], w4 = wsh[o*9+4], w5 = wsh[o*9+5];
    float w6 = wsh[o*9+6], w7 = wsh[o*9+7], w8 = wsh[o*9+8];
    float bias = bsh[o];
    float* yout = ws + YCOFF + ((size_t)b * OCH + o) * (OH * OW) + h * OW;
    const float* r0 = &xs[(h + 0) * 20];
    const float* r1 = &xs[(h + 1) * 20];
    const float* r2 = &xs[(h + 2) * 20];
    #pragma unroll
    for (int wd = 0; wd < OW; wd++) {
        float acc = bias;
        acc = fmaf(r0[wd+0], w0, acc); acc = fmaf(r0[wd+1], w1, acc); acc = fmaf(r0[wd+2], w2, acc);
        acc = fmaf(r1[wd+0], w3, acc); acc = fmaf(r1[wd+1], w4, acc); acc = fmaf(r1[wd+2], w5, acc);
        acc = fmaf(r2[wd+0], w6, acc); acc = fmaf(r2[wd+1], w7, acc); acc = fmaf(r2[wd+2], w8, acc);
        yout[wd] = acc;
    }
}

// k3a: bn1 partial stats — 8 slices per channel, 256 blocks
__global__ __launch_bounds__(256) void k3a_bn1(float* __restrict__ ws) {
    __shared__ float red[256], red2[256];
    int o = blockIdx.x >> 3, sl = blockIdx.x & 7;
    int tid = threadIdx.x;
    const float* yc = ws + YCOFF;
    const int per = (BATCH * OH * OW) / 8;   // 9216
    float s = 0.f, s2 = 0.f;
    for (int i = sl * per + tid; i < (sl + 1) * per; i += 256) {
        int b = i / (OH * OW);
        int p = i - b * (OH * OW);
        float v = yc[((size_t)b * OCH + o) * (OH * OW) + p];
        s += v; s2 += v * v;
    }
    red[tid] = s; red2[tid] = s2;
    __syncthreads();
    for (int off = 128; off; off >>= 1) {
        if (tid < off) { red[tid] += red[tid + off]; red2[tid] += red2[tid + off]; }
        __syncthreads();
    }
    if (tid == 0) {
        ws[K3P + 2 * blockIdx.x + 0] = red[0];
        ws[K3P + 2 * blockIdx.x + 1] = red2[0];
    }
}

// k3b: finalize bn1 -> scale/shift
__global__ __launch_bounds__(256) void k3b_bn1(const float* __restrict__ g1,
                                               const float* __restrict__ b1,
                                               float* __restrict__ ws) {
    __shared__ float rs[256], rq[256];
    int tid = threadIdx.x;
    rs[tid] = ws[K3P + 2 * tid + 0];
    rq[tid] = ws[K3P + 2 * tid + 1];
    __syncthreads();
    if (tid < OCH) {
        float sm = 0.f, sq = 0.f;
        #pragma unroll
        for (int sl = 0; sl < 8; sl++) { sm += rs[tid * 8 + sl]; sq += rq[tid * 8 + sl]; }
        const float inv = 1.0f / (BATCH * OH * OW);
        float m = sm * inv;
        float var = sq * inv - m * m;
        float a = rsqrtf(var + EPSV) * g1[tid];
        ws[BN1 + tid] = a;
        ws[BN1 + 32 + tid] = b1[tid] - m * a;
    }
}

// k4: FC GEMM partials (fp32, K-split): 32x32 tile, 448 blocks, K-chunk 64
__global__ __launch_bounds__(256) void k4_fc(float* __restrict__ ws,
                                             const float* __restrict__ fcw) {
    __shared__ float As[64][34];
    __shared__ float Bs[64][34];
    const float* yc = ws + YCOFF;
    const float* bn1p = ws + BN1;
    int tid = threadIdx.x;
    int tx = tid & 15, ty = tid >> 4;      // tx -> n pair, ty -> m pair
    int j0 = blockIdx.x * 32;              // 0..192 (covers 224 padded)
    int m0 = blockIdx.y * 32;
    int kbase = blockIdx.z * (FCK / KSPLIT);
    float* part = ws + PART + (size_t)blockIdx.z * BATCH * EDIM;
    float acc00 = 0.f, acc01 = 0.f, acc10 = 0.f, acc11 = 0.f;

    for (int kc = 0; kc < FCK / KSPLIT; kc += 64) {
        // stage A: 32 m x 64 k, bn1+relu applied; tasks = 32m x 16 kgroups(float4)
        for (int idx = tid; idx < 512; idx += 256) {
            int kg = idx & 15, mm = idx >> 4;
            int gk = kbase + kc + kg * 4;
            int o = gk / 144;                       // 4-group never straddles 144
            float sc = bn1p[o], sh = bn1p[32 + o];
            float4 v = *(const float4*)&yc[(size_t)(m0 + mm) * FCK + gk];
            float t0 = fmaf(v.x, sc, sh); t0 = t0 > 0.f ? t0 : 0.f;
            float t1 = fmaf(v.y, sc, sh); t1 = t1 > 0.f ? t1 : 0.f;
            float t2 = fmaf(v.z, sc, sh); t2 = t2 > 0.f ? t2 : 0.f;
            float t3 = fmaf(v.w, sc, sh); t3 = t3 > 0.f ? t3 : 0.f;
            As[kg * 4 + 0][mm] = t0;
            As[kg * 4 + 1][mm] = t1;
            As[kg * 4 + 2][mm] = t2;
            As[kg * 4 + 3][mm] = t3;
        }
        // stage B: 32 j x 64 k from fcw (zero-fill j >= EDIM)
        for (int idx = tid; idx < 512; idx += 256) {
            int kg = idx & 15, jj = idx >> 4;
            int gj = j0 + jj;
            float4 v = {0.f, 0.f, 0.f, 0.f};
            if (gj < EDIM)
                v = *(const float4*)&fcw[(size_t)gj * FCK + kbase + kc + kg * 4];
            Bs[kg * 4 + 0][jj] = v.x;
            Bs[kg * 4 + 1][jj] = v.y;
            Bs[kg * 4 + 2][jj] = v.z;
            Bs[kg * 4 + 3][jj] = v.w;
        }
        __syncthreads();
        #pragma unroll
        for (int kk = 0; kk < 64; kk++) {
            float2 a = *(const float2*)&As[kk][ty * 2];
            float2 b = *(const float2*)&Bs[kk][tx * 2];
            acc00 = fmaf(a.x, b.x, acc00);
            acc01 = fmaf(a.x, b.y, acc01);
            acc10 = fmaf(a.y, b.x, acc10);
            acc11 = fmaf(a.y, b.y, acc11);
        }
        __syncthreads();
    }
    {
        int m = m0 + ty * 2;
        int gj = j0 + tx * 2;
        if (gj + 0 < EDIM) part[(m + 0) * EDIM + gj + 0] = acc00;
        if (gj + 1 < EDIM) part[(m + 0) * EDIM + gj + 1] = acc01;
        if (gj + 0 < EDIM) part[(m + 1) * EDIM + gj + 0] = acc10;
        if (gj + 1 < EDIM) part[(m + 1) * EDIM + gj + 1] = acc11;
    }
}

// k5: y2 = sum_z part + fc_b; bn2; A = relu(bn2(y2)) split to bf16 hi/lo [512][224]
__global__ __launch_bounds__(256) void k5_bn2(const float* __restrict__ g2,
                                              const float* __restrict__ b2,
                                              const float* __restrict__ fcb,
                                              float* __restrict__ ws) {
    unsigned short* gAh = (unsigned short*)(ws + AHI);
    unsigned short* gAl = (unsigned short*)(ws + ALO);
    int j = blockIdx.x, tid = threadIdx.x;
    if (j >= EDIM) {   // zero padding columns 200..223
        for (int b = tid; b < BATCH; b += 256) {
            gAh[(size_t)b * KPAD + j] = 0;
            gAl[(size_t)b * KPAD + j] = 0;
        }
        return;
    }
    __shared__ float red[256], red2[256];
    __shared__ float ss[2];
    const float* part = ws + PART;
    float bias = fcb[j];
    float v0 = bias, v1 = bias;
    #pragma unroll
    for (int z = 0; z < KSPLIT; z++) {
        v0 += part[(size_t)z * BATCH * EDIM + tid * EDIM + j];
        v1 += part[(size_t)z * BATCH * EDIM + (tid + 256) * EDIM + j];
    }
    red[tid] = v0 + v1; red2[tid] = v0 * v0 + v1 * v1;
    __syncthreads();
    for (int off = 128; off; off >>= 1) {
        if (tid < off) { red[tid] += red[tid + off]; red2[tid] += red2[tid + off]; }
        __syncthreads();
    }
    if (tid == 0) {
        const float inv = 1.0f / BATCH;
        float m = red[0] * inv;
        float var = red2[0] * inv - m * m;
        float a = rsqrtf(var + EPSV) * g2[j];
        ss[0] = a;
        ss[1] = b2[j] - m * a;
    }
    __syncthreads();
    float a = ss[0], s = ss[1];
    float r0 = fmaf(v0, a, s); r0 = r0 > 0.f ? r0 : 0.f;
    float r1 = fmaf(v1, a, s); r1 = r1 > 0.f ? r1 : 0.f;
    unsigned short h, l;
    split_bf16(r0, h, l);
    gAh[(size_t)tid * KPAD + j] = h;  gAl[(size_t)tid * KPAD + j] = l;
    split_bf16(r1, h, l);
    gAh[(size_t)(tid + 256) * KPAD + j] = h;  gAl[(size_t)(tid + 256) * KPAD + j] = l;
}

// k6: logits = sigmoid( A @ emb^T + bias_e ), split-bf16 3-pass MFMA.
//  - block tile = 64 ents (n) x 512 batch rows (m, full batch); 1024 thr / 16 waves
//  - B-tile staged once to LDS (57 KB), one barrier before K-loop
//  - A fragments per-lane from global (458 KB, L2-resident)
//  - epilogue: sigmoid in place -> per-wave LDS transpose (reusing dead B LDS)
//    -> nontemporal 256B-contiguous f32x4 stores (ext_vector type: the builtin
//    rejects HIP's struct float4). Values and FP order unchanged -> bit-identical.
__global__ __launch_bounds__(1024) void k6_gemm(const float* __restrict__ ws,
                                                const float* __restrict__ emb,
                                                const float* __restrict__ be,
                                                float* __restrict__ out) {
    __shared__ unsigned short Bh[14336];   // 28672 B
    __shared__ unsigned short Bl[14336];   // 28672 B
    const unsigned short* gAh = (const unsigned short*)(ws + AHI);
    const unsigned short* gAl = (const unsigned short*)(ws + ALO);
    int tid = threadIdx.x;
    int n0 = blockIdx.x * 64;

    // ---- stage B tile: 64 ents x 28 k-chunks of 8, fp32 -> split hi/lo ----
    // slot = (g*28 + kch)*16 + col  (g = ent>>4, col = ent&15); 1792 slots x 16B
    for (int idx = tid; idx < 1792; idx += 1024) {
        int col = idx & 15;
        int t   = idx >> 4;          // g*28 + kch
        int g   = t / 28;
        int kch = t - g * 28;
        int gn  = n0 + g * 16 + col;
        float4 va = {0.f, 0.f, 0.f, 0.f};
        float4 vb = {0.f, 0.f, 0.f, 0.f};
        if (gn < NUM_ENT && kch < 25) {                // 25*8 = 200 = EDIM exactly
            const float* row = &emb[(size_t)gn * EDIM + kch * 8];
            va = *(const float4*)row;
            vb = *(const float4*)(row + 4);
        }
        unsigned short h0,h1,h2,h3,h4,h5,h6,h7, l0,l1,l2,l3,l4,l5,l6,l7;
        split_bf16(va.x, h0, l0); split_bf16(va.y, h1, l1);
        split_bf16(va.z, h2, l2); split_bf16(va.w, h3, l3);
        split_bf16(vb.x, h4, l4); split_bf16(vb.y, h5, l5);
        split_bf16(vb.z, h6, l6); split_bf16(vb.w, h7, l7);
        uint4 uh, ul;
        uh.x = (unsigned)h0 | ((unsigned)h1 << 16);
        uh.y = (unsigned)h2 | ((unsigned)h3 << 16);
        uh.z = (unsigned)h4 | ((unsigned)h5 << 16);
        uh.w = (unsigned)h6 | ((unsigned)h7 << 16);
        ul.x = (unsigned)l0 | ((unsigned)l1 << 16);
        ul.y = (unsigned)l2 | ((unsigned)l3 << 16);
        ul.z = (unsigned)l4 | ((unsigned)l5 << 16);
        ul.w = (unsigned)l6 | ((unsigned)l7 << 16);
        *(uint4*)&Bh[idx * 8] = uh;
        *(uint4*)&Bl[idx * 8] = ul;
    }
    __syncthreads();

    // ---- compute: wave mq in [0,16) -> rows mq*32..mq*32+31 ; all 64 n ----
    int lane = tid & 63, col = lane & 15, quad = lane >> 4;
    int mq = tid >> 6;

    f32x4 acc[2][4];
    #pragma unroll
    for (int i = 0; i < 2; i++)
        #pragma unroll
        for (int j = 0; j < 4; j++)
            acc[i][j] = (f32x4){0.f, 0.f, 0.f, 0.f};

    int arow = mq * 32 + col;

    for (int kc = 0; kc < KPAD; kc += 32) {            // 7 iters, no barriers
        bf16x8 ah[2], al[2], bh[4], bl[4];
        #pragma unroll
        for (int i = 0; i < 2; i++) {
            size_t aoff = (size_t)(arow + i * 16) * KPAD + kc + quad * 8;
            ah[i] = *(const bf16x8*)&gAh[aoff];
            al[i] = *(const bf16x8*)&gAl[aoff];
        }
        #pragma unroll
        for (int j = 0; j < 4; j++) {
            int boff = ((j * 28 + (kc >> 3) + quad) * 16 + col) * 8;
            bh[j] = *(const bf16x8*)&Bh[boff];
            bl[j] = *(const bf16x8*)&Bl[boff];
        }
        #pragma unroll
        for (int i = 0; i < 2; i++)
            #pragma unroll
            for (int j = 0; j < 4; j++) {
                acc[i][j] = __builtin_amdgcn_mfma_f32_16x16x32_bf16(ah[i], bh[j], acc[i][j], 0, 0, 0);
                acc[i][j] = __builtin_amdgcn_mfma_f32_16x16x32_bf16(ah[i], bl[j], acc[i][j], 0, 0, 0);
                acc[i][j] = __builtin_amdgcn_mfma_f32_16x16x32_bf16(al[i], bh[j], acc[i][j], 0, 0, 0);
            }
    }

    // ---- epilogue ----
    // 1) sigmoid in place (full EXEC, identical FP expression/order as before)
    #pragma unroll
    for (int j = 0; j < 4; j++) {
        int n = n0 + j * 16 + col;
        float bv = (n < NUM_ENT) ? be[n] : 0.f;
        #pragma unroll
        for (int i = 0; i < 2; i++)
            #pragma unroll
            for (int r = 0; r < 4; r++)
                acc[i][j][r] = sigf(acc[i][j][r] + bv);
    }
    // 2) B LDS is dead for every wave now -> reuse as transpose scratch
    __syncthreads();
    float* tr = ((float*)Bh) + mq * 272;   // per-wave 4 rows x 68 floats (padded)

    // 3) 8 row-groups of 4 rows; each group: quad q's 16 lanes scatter their
    //    16 values, all 64 lanes read back contiguously and store 256B segments
    #pragma unroll
    for (int rg = 0; rg < 8; rg++) {
        int i = rg >> 2, q = rg & 3;
        if (quad == q) {
            #pragma unroll
            for (int j = 0; j < 4; j++)
                #pragma unroll
                for (int r = 0; r < 4; r++)
                    tr[r * 68 + j * 16 + col] = acc[i][j][r];
        }
        f32x4 v = *(const f32x4*)&tr[(lane >> 4) * 68 + (lane & 15) * 4];
        int row = mq * 32 + i * 16 + q * 4 + (lane >> 4);
        int nb = n0 + (lane & 15) * 4;
        if (nb + 3 < NUM_ENT)
            __builtin_nontemporal_store(v, (f32x4*)&out[(size_t)row * NUM_ENT + nb]);
    }
}

extern "C" void kernel_launch(void* const* d_in, const int* in_sizes, int n_in,
                              void* d_out, int out_size, void* d_ws, size_t ws_size,
                              hipStream_t stream) {
    const int*   e1  = (const int*)d_in[0];
    const int*   rel = (const int*)d_in[1];
    const float* emb = (const float*)d_in[2];
    const float* cw  = (const float*)d_in[3];
    const float* cb  = (const float*)d_in[4];
    const float* g0  = (const float*)d_in[5];
    const float* b0  = (const float*)d_in[6];
    const float* g1  = (const float*)d_in[7];
    const float* b1  = (const float*)d_in[8];
    const float* g2  = (const float*)d_in[9];
    const float* b2  = (const float*)d_in[10];
    const float* fcw = (const float*)d_in[11];
    const float* fcb = (const float*)d_in[12];
    const float* be  = (const float*)d_in[13];
    float* ws  = (float*)d_ws;
    float* out = (float*)d_out;

    k1a_bn0<<<64, 256, 0, stream>>>(e1, emb, ws);
    k1b_bn0<<<1, 64, 0, stream>>>(g0, ws);
    k2_conv<<<BATCH, 256, 0, stream>>>(e1, rel, emb, cw, cb, b0, ws);
    k3a_bn1<<<256, 256, 0, stream>>>(ws);
    k3b_bn1<<<1, 256, 0, stream>>>(g1, b1, ws);
    k4_fc  <<<dim3(7, 16, KSPLIT), 256, 0, stream>>>(ws, fcw);
    k5_bn2 <<<KPAD, 256, 0, stream>>>(g2, b2, fcb, ws);
    k6_gemm<<<1563, 1024, 0, stream>>>(ws, emb, be, out);
}

// Round 7
// 448.057 us; speedup vs baseline: 1.5518x; 1.0031x over previous
//
#include <hip/hip_runtime.h>
#include <hip/hip_bf16.h>

// ---------------- problem constants ----------------
#define BATCH   512
#define NUM_ENT 100000
#define EDIM    200
#define KPAD    224         // EDIM padded to multiple of 32
#define OCH     32          // conv out channels
#define OH      8
#define OW      18
#define FCK     4608        // 32*8*18
#define EPSV    1e-5f
#define KSPLIT  4           // k4 K-split factor (K chunk = 1152)

// ---------------- ws layout (float offsets) ----------------
#define WS0   0        // [2]    bn0: mean, rs*g0
#define BN1   8        // [64]   bn1: scale[32], shift[32]
#define K1P   512      // [128]  bn0 per-block partials
#define K3P   704      // [512]  bn1 per-block partials (256 blocks x {sum,sumsq})
#define YCOFF 2048     // [512*32*8*18] = 2359296 -> ends 2361344
#define PART  2361344  // [KSPLIT*512*200] = 409600 -> ends 2770944 (11.08 MB)
// A hi/lo (bf16) overlap the yc region (yc dead after k4):
#define AHI   2048     // 512*224 ushorts = 57344 floats -> ends 59392
#define ALO   59392    // 512*224 ushorts -> ends 116736 (< PART, no overlap)

typedef short bf16x8 __attribute__((ext_vector_type(8)));
typedef float f32x4  __attribute__((ext_vector_type(4)));

__device__ __forceinline__ float sigf(float x) {
    return 1.0f / (1.0f + __expf(-x));
}

__device__ __forceinline__ unsigned short bf16_rn(float v) {
    unsigned int u = __float_as_uint(v);
    unsigned int r = (u + 0x7FFFu + ((u >> 16) & 1u)) >> 16;
    return (unsigned short)r;
}

__device__ __forceinline__ void split_bf16(float v, unsigned short& hi, unsigned short& lo) {
    hi = bf16_rn(v);
    float hf = __uint_as_float(((unsigned int)hi) << 16);
    lo = bf16_rn(v - hf);
}

// k1a: bn0 partial sums over gathered embeddings
__global__ __launch_bounds__(256) void k1a_bn0(const int* __restrict__ e1,
                                               const float* __restrict__ emb,
                                               float* __restrict__ ws) {
    __shared__ float red[256], red2[256];
    int tid = threadIdx.x;
    int base = blockIdx.x * 1600;
    float s = 0.f, s2 = 0.f;
    for (int i = base + tid; i < base + 1600; i += 256) {
        int b = i / EDIM;
        int k = i - b * EDIM;
        float v = emb[(size_t)e1[b] * EDIM + k];
        s += v; s2 += v * v;
    }
    red[tid] = s; red2[tid] = s2;
    __syncthreads();
    for (int off = 128; off; off >>= 1) {
        if (tid < off) { red[tid] += red[tid + off]; red2[tid] += red2[tid + off]; }
        __syncthreads();
    }
    if (tid == 0) {
        ws[K1P + 2 * blockIdx.x + 0] = red[0];
        ws[K1P + 2 * blockIdx.x + 1] = red2[0];
    }
}

// k1b: finalize bn0
__global__ __launch_bounds__(64) void k1b_bn0(const float* __restrict__ g0,
                                              float* __restrict__ ws) {
    __shared__ float red[64], red2[64];
    int tid = threadIdx.x;
    red[tid]  = ws[K1P + 2 * tid + 0];
    red2[tid] = ws[K1P + 2 * tid + 1];
    __syncthreads();
    for (int off = 32; off; off >>= 1) {
        if (tid < off) { red[tid] += red[tid + off]; red2[tid] += red2[tid + off]; }
        __syncthreads();
    }
    if (tid == 0) {
        const float inv = 1.0f / (BATCH * EDIM);
        float m = red[0] * inv;
        float var = red2[0] * inv - m * m;
        ws[WS0 + 0] = m;
        ws[WS0 + 1] = rsqrtf(var + EPSV) * g0[0];
    }
}

// k2: relation-indexed 3x3 conv on bn0-normalized x
__global__ __launch_bounds__(256) void k2_conv(const int* __restrict__ e1,
                                               const int* __restrict__ rel,
                                               const float* __restrict__ emb,
                                               const float* __restrict__ cw,
                                               const float* __restrict__ cb,
                                               const float* __restrict__ b0,
                                               float* __restrict__ ws) {
    __shared__ float xs[EDIM];
    __shared__ float wsh[OCH * 9];
    __shared__ float bsh[OCH];
    int b = blockIdx.x, tid = threadIdx.x;
    float m = ws[WS0 + 0], s = ws[WS0 + 1], b0v = b0[0];
    int r = rel[b];
    if (tid < EDIM) xs[tid] = fmaf(emb[(size_t)e1[b] * EDIM + tid] - m, s, b0v);
    for (int i = tid; i < OCH * 9; i += 256) wsh[i] = cw[(size_t)r * OCH * 9 + i];
    if (tid < OCH) bsh[tid] = cb[r * OCH + tid];
    __syncthreads();
    int o = tid >> 3, h = tid & 7;
    float w0 = wsh[o*9+0], w1 = wsh[o*9+1], w2 = wsh[o*9+2];
    float w3 = wsh[o*9+3], w4 = wsh[o*9+4], w5 = wsh[o*9+5];
    float w6 = wsh[o*9+6], w7 = wsh[o*9+7], w8 = wsh[o*9+8];
    float bias = bsh[o];
    float* yout = ws + YCOFF + ((size_t)b * OCH + o) * (OH * OW) + h * OW;
    const float* r0 = &xs[(h + 0) * 20];
    const float* r1 = &xs[(h + 1) * 20];
    const float* r2 = &xs[(h + 2) * 20];
    #pragma unroll
    for (int wd = 0; wd < OW; wd++) {
        float acc = bias;
        acc = fmaf(r0[wd+0], w0, acc); acc = fmaf(r0[wd+1], w1, acc); acc = fmaf(r0[wd+2], w2, acc);
        acc = fmaf(r1[wd+0], w3, acc); acc = fmaf(r1[wd+1], w4, acc); acc = fmaf(r1[wd+2], w5, acc);
        acc = fmaf(r2[wd+0], w6, acc); acc = fmaf(r2[wd+1], w7, acc); acc = fmaf(r2[wd+2], w8, acc);
        yout[wd] = acc;
    }
}

// k3a: bn1 partial stats — 8 slices per channel, 256 blocks
__global__ __launch_bounds__(256) void k3a_bn1(float* __restrict__ ws) {
    __shared__ float red[256], red2[256];
    int o = blockIdx.x >> 3, sl = blockIdx.x & 7;
    int tid = threadIdx.x;
    const float* yc = ws + YCOFF;
    const int per = (BATCH * OH * OW) / 8;   // 9216
    float s = 0.f, s2 = 0.f;
    for (int i = sl * per + tid; i < (sl + 1) * per; i += 256) {
        int b = i / (OH * OW);
        int p = i - b * (OH * OW);
        float v = yc[((size_t)b * OCH + o) * (OH * OW) + p];
        s += v; s2 += v * v;
    }
    red[tid] = s; red2[tid] = s2;
    __syncthreads();
    for (int off = 128; off; off >>= 1) {
        if (tid < off) { red[tid] += red[tid + off]; red2[tid] += red2[tid + off]; }
        __syncthreads();
    }
    if (tid == 0) {
        ws[K3P + 2 * blockIdx.x + 0] = red[0];
        ws[K3P + 2 * blockIdx.x + 1] = red2[0];
    }
}

// k3b: finalize bn1 -> scale/shift
__global__ __launch_bounds__(256) void k3b_bn1(const float* __restrict__ g1,
                                               const float* __restrict__ b1,
                                               float* __restrict__ ws) {
    __shared__ float rs[256], rq[256];
    int tid = threadIdx.x;
    rs[tid] = ws[K3P + 2 * tid + 0];
    rq[tid] = ws[K3P + 2 * tid + 1];
    __syncthreads();
    if (tid < OCH) {
        float sm = 0.f, sq = 0.f;
        #pragma unroll
        for (int sl = 0; sl < 8; sl++) { sm += rs[tid * 8 + sl]; sq += rq[tid * 8 + sl]; }
        const float inv = 1.0f / (BATCH * OH * OW);
        float m = sm * inv;
        float var = sq * inv - m * m;
        float a = rsqrtf(var + EPSV) * g1[tid];
        ws[BN1 + tid] = a;
        ws[BN1 + 32 + tid] = b1[tid] - m * a;
    }
}

// k4: FC GEMM partials (fp32, K-split): 32x32 tile, 448 blocks, K-chunk 64
__global__ __launch_bounds__(256) void k4_fc(float* __restrict__ ws,
                                             const float* __restrict__ fcw) {
    __shared__ float As[64][34];
    __shared__ float Bs[64][34];
    const float* yc = ws + YCOFF;
    const float* bn1p = ws + BN1;
    int tid = threadIdx.x;
    int tx = tid & 15, ty = tid >> 4;      // tx -> n pair, ty -> m pair
    int j0 = blockIdx.x * 32;              // 0..192 (covers 224 padded)
    int m0 = blockIdx.y * 32;
    int kbase = blockIdx.z * (FCK / KSPLIT);
    float* part = ws + PART + (size_t)blockIdx.z * BATCH * EDIM;
    float acc00 = 0.f, acc01 = 0.f, acc10 = 0.f, acc11 = 0.f;

    for (int kc = 0; kc < FCK / KSPLIT; kc += 64) {
        // stage A: 32 m x 64 k, bn1+relu applied; tasks = 32m x 16 kgroups(float4)
        for (int idx = tid; idx < 512; idx += 256) {
            int kg = idx & 15, mm = idx >> 4;
            int gk = kbase + kc + kg * 4;
            int o = gk / 144;                       // 4-group never straddles 144
            float sc = bn1p[o], sh = bn1p[32 + o];
            float4 v = *(const float4*)&yc[(size_t)(m0 + mm) * FCK + gk];
            float t0 = fmaf(v.x, sc, sh); t0 = t0 > 0.f ? t0 : 0.f;
            float t1 = fmaf(v.y, sc, sh); t1 = t1 > 0.f ? t1 : 0.f;
            float t2 = fmaf(v.z, sc, sh); t2 = t2 > 0.f ? t2 : 0.f;
            float t3 = fmaf(v.w, sc, sh); t3 = t3 > 0.f ? t3 : 0.f;
            As[kg * 4 + 0][mm] = t0;
            As[kg * 4 + 1][mm] = t1;
            As[kg * 4 + 2][mm] = t2;
            As[kg * 4 + 3][mm] = t3;
        }
        // stage B: 32 j x 64 k from fcw (zero-fill j >= EDIM)
        for (int idx = tid; idx < 512; idx += 256) {
            int kg = idx & 15, jj = idx >> 4;
            int gj = j0 + jj;
            float4 v = {0.f, 0.f, 0.f, 0.f};
            if (gj < EDIM)
                v = *(const float4*)&fcw[(size_t)gj * FCK + kbase + kc + kg * 4];
            Bs[kg * 4 + 0][jj] = v.x;
            Bs[kg * 4 + 1][jj] = v.y;
            Bs[kg * 4 + 2][jj] = v.z;
            Bs[kg * 4 + 3][jj] = v.w;
        }
        __syncthreads();
        #pragma unroll
        for (int kk = 0; kk < 64; kk++) {
            float2 a = *(const float2*)&As[kk][ty * 2];
            float2 b = *(const float2*)&Bs[kk][tx * 2];
            acc00 = fmaf(a.x, b.x, acc00);
            acc01 = fmaf(a.x, b.y, acc01);
            acc10 = fmaf(a.y, b.x, acc10);
            acc11 = fmaf(a.y, b.y, acc11);
        }
        __syncthreads();
    }
    {
        int m = m0 + ty * 2;
        int gj = j0 + tx * 2;
        if (gj + 0 < EDIM) part[(m + 0) * EDIM + gj + 0] = acc00;
        if (gj + 1 < EDIM) part[(m + 0) * EDIM + gj + 1] = acc01;
        if (gj + 0 < EDIM) part[(m + 1) * EDIM + gj + 0] = acc10;
        if (gj + 1 < EDIM) part[(m + 1) * EDIM + gj + 1] = acc11;
    }
}

// k5: y2 = sum_z part + fc_b; bn2; A = relu(bn2(y2)) split to bf16 hi/lo [512][224]
__global__ __launch_bounds__(256) void k5_bn2(const float* __restrict__ g2,
                                              const float* __restrict__ b2,
                                              const float* __restrict__ fcb,
                                              float* __restrict__ ws) {
    unsigned short* gAh = (unsigned short*)(ws + AHI);
    unsigned short* gAl = (unsigned short*)(ws + ALO);
    int j = blockIdx.x, tid = threadIdx.x;
    if (j >= EDIM) {   // zero padding columns 200..223
        for (int b = tid; b < BATCH; b += 256) {
            gAh[(size_t)b * KPAD + j] = 0;
            gAl[(size_t)b * KPAD + j] = 0;
        }
        return;
    }
    __shared__ float red[256], red2[256];
    __shared__ float ss[2];
    const float* part = ws + PART;
    float bias = fcb[j];
    float v0 = bias, v1 = bias;
    #pragma unroll
    for (int z = 0; z < KSPLIT; z++) {
        v0 += part[(size_t)z * BATCH * EDIM + tid * EDIM + j];
        v1 += part[(size_t)z * BATCH * EDIM + (tid + 256) * EDIM + j];
    }
    red[tid] = v0 + v1; red2[tid] = v0 * v0 + v1 * v1;
    __syncthreads();
    for (int off = 128; off; off >>= 1) {
        if (tid < off) { red[tid] += red[tid + off]; red2[tid] += red2[tid + off]; }
        __syncthreads();
    }
    if (tid == 0) {
        const float inv = 1.0f / BATCH;
        float m = red[0] * inv;
        float var = red2[0] * inv - m * m;
        float a = rsqrtf(var + EPSV) * g2[j];
        ss[0] = a;
        ss[1] = b2[j] - m * a;
    }
    __syncthreads();
    float a = ss[0], s = ss[1];
    float r0 = fmaf(v0, a, s); r0 = r0 > 0.f ? r0 : 0.f;
    float r1 = fmaf(v1, a, s); r1 = r1 > 0.f ? r1 : 0.f;
    unsigned short h, l;
    split_bf16(r0, h, l);
    gAh[(size_t)tid * KPAD + j] = h;  gAl[(size_t)tid * KPAD + j] = l;
    split_bf16(r1, h, l);
    gAh[(size_t)(tid + 256) * KPAD + j] = h;  gAl[(size_t)(tid + 256) * KPAD + j] = l;
}

// k6: logits = sigmoid( A @ emb^T + bias_e ), split-bf16 3-pass MFMA.
//  - block tile = 64 ents (n) x 512 batch rows (m); 1024 thr / 16 waves
//  - B-tile staged once to LDS (57 KB), one barrier before K-loop
//  - A fragments: INLINE-ASM global_load_dwordx4 2-deep pipeline with counted
//    s_waitcnt vmcnt(4) (compiler kept sinking plain loads -> VGPR 56, serial
//    L2 latency; asm loads cannot be sunk/rematerialized). sched_barrier(0)
//    after each waitcnt (rule: MFMA can hoist past asm waitcnt otherwise).
//  - epilogue: sigmoid in place -> per-wave LDS transpose -> nontemporal
//    256B-contiguous f32x4 stores. FP order unchanged -> bit-identical.
__global__ __launch_bounds__(1024) void k6_gemm(const float* __restrict__ ws,
                                                const float* __restrict__ emb,
                                                const float* __restrict__ be,
                                                float* __restrict__ out) {
    __shared__ unsigned short Bh[14336];   // 28672 B
    __shared__ unsigned short Bl[14336];   // 28672 B
    const unsigned short* gAh = (const unsigned short*)(ws + AHI);
    const unsigned short* gAl = (const unsigned short*)(ws + ALO);
    int tid = threadIdx.x;
    int n0 = blockIdx.x * 64;

    // ---- stage B tile: 64 ents x 28 k-chunks of 8, fp32 -> split hi/lo ----
    for (int idx = tid; idx < 1792; idx += 1024) {
        int col = idx & 15;
        int t   = idx >> 4;          // g*28 + kch
        int g   = t / 28;
        int kch = t - g * 28;
        int gn  = n0 + g * 16 + col;
        float4 va = {0.f, 0.f, 0.f, 0.f};
        float4 vb = {0.f, 0.f, 0.f, 0.f};
        if (gn < NUM_ENT && kch < 25) {                // 25*8 = 200 = EDIM exactly
            const float* row = &emb[(size_t)gn * EDIM + kch * 8];
            va = *(const float4*)row;
            vb = *(const float4*)(row + 4);
        }
        unsigned short h0,h1,h2,h3,h4,h5,h6,h7, l0,l1,l2,l3,l4,l5,l6,l7;
        split_bf16(va.x, h0, l0); split_bf16(va.y, h1, l1);
        split_bf16(va.z, h2, l2); split_bf16(va.w, h3, l3);
        split_bf16(vb.x, h4, l4); split_bf16(vb.y, h5, l5);
        split_bf16(vb.z, h6, l6); split_bf16(vb.w, h7, l7);
        uint4 uh, ul;
        uh.x = (unsigned)h0 | ((unsigned)h1 << 16);
        uh.y = (unsigned)h2 | ((unsigned)h3 << 16);
        uh.z = (unsigned)h4 | ((unsigned)h5 << 16);
        uh.w = (unsigned)h6 | ((unsigned)h7 << 16);
        ul.x = (unsigned)l0 | ((unsigned)l1 << 16);
        ul.y = (unsigned)l2 | ((unsigned)l3 << 16);
        ul.z = (unsigned)l4 | ((unsigned)l5 << 16);
        ul.w = (unsigned)l6 | ((unsigned)l7 << 16);
        *(uint4*)&Bh[idx * 8] = uh;
        *(uint4*)&Bl[idx * 8] = ul;
    }
    __syncthreads();   // drains vmcnt to 0 -> clean baseline for counted waits

    // ---- compute: wave mq in [0,16) -> rows mq*32..mq*32+31 ; all 64 n ----
    int lane = tid & 63, col = lane & 15, quad = lane >> 4;
    int mq = tid >> 6;

    f32x4 acc[2][4];
    #pragma unroll
    for (int i = 0; i < 2; i++)
        #pragma unroll
        for (int j = 0; j < 4; j++)
            acc[i][j] = (f32x4){0.f, 0.f, 0.f, 0.f};

    int arow = mq * 32 + col;
    const unsigned short* pAh0 = gAh + (size_t)arow * KPAD + quad * 8;
    const unsigned short* pAh1 = gAh + (size_t)(arow + 16) * KPAD + quad * 8;
    const unsigned short* pAl0 = gAl + (size_t)arow * KPAD + quad * 8;
    const unsigned short* pAl1 = gAl + (size_t)(arow + 16) * KPAD + quad * 8;

    bf16x8 Ah0a, Ah1a, Al0a, Al1a;   // pipeline buffer a
    bf16x8 Ah0b, Ah1b, Al0b, Al1b;   // pipeline buffer b

    // issue 4 A-fragment loads for K-tile T (byte offset T*64 = T*32 ushorts)
#define K6_ISSUE(T, H0, H1, L0, L1)                                            \
    asm volatile("global_load_dwordx4 %0, %1, off offset:%c2"                  \
                 : "=&v"(H0) : "v"(pAh0), "i"((T) * 64) : "memory");           \
    asm volatile("global_load_dwordx4 %0, %1, off offset:%c2"                  \
                 : "=&v"(H1) : "v"(pAh1), "i"((T) * 64) : "memory");           \
    asm volatile("global_load_dwordx4 %0, %1, off offset:%c2"                  \
                 : "=&v"(L0) : "v"(pAl0), "i"((T) * 64) : "memory");           \
    asm volatile("global_load_dwordx4 %0, %1, off offset:%c2"                  \
                 : "=&v"(L1) : "v"(pAl1), "i"((T) * 64) : "memory");

#define K6_WAIT(N)                                                             \
    asm volatile("s_waitcnt vmcnt(" #N ")" ::: "memory");                      \
    __builtin_amdgcn_sched_barrier(0);

    // per-acc update order identical to prior rounds: t ascending; hh, hl, lh
#define K6_MFMA(T, H0, H1, L0, L1)                                             \
    {                                                                          \
        bf16x8 bh[4], bl[4];                                                   \
        _Pragma("unroll")                                                      \
        for (int j = 0; j < 4; j++) {                                          \
            int boff = ((j * 28 + (T) * 4 + quad) * 16 + col) * 8;             \
            bh[j] = *(const bf16x8*)&Bh[boff];                                 \
            bl[j] = *(const bf16x8*)&Bl[boff];                                 \
        }                                                                      \
        _Pragma("unroll")                                                      \
        for (int j = 0; j < 4; j++) {                                          \
            acc[0][j] = __builtin_amdgcn_mfma_f32_16x16x32_bf16(H0, bh[j], acc[0][j], 0, 0, 0); \
            acc[0][j] = __builtin_amdgcn_mfma_f32_16x16x32_bf16(H0, bl[j], acc[0][j], 0, 0, 0); \
            acc[0][j] = __builtin_amdgcn_mfma_f32_16x16x32_bf16(L0, bh[j], acc[0][j], 0, 0, 0); \
            acc[1][j] = __builtin_amdgcn_mfma_f32_16x16x32_bf16(H1, bh[j], acc[1][j], 0, 0, 0); \
            acc[1][j] = __builtin_amdgcn_mfma_f32_16x16x32_bf16(H1, bl[j], acc[1][j], 0, 0, 0); \
            acc[1][j] = __builtin_amdgcn_mfma_f32_16x16x32_bf16(L1, bh[j], acc[1][j], 0, 0, 0); \
        }                                                                      \
    }

    K6_ISSUE(0, Ah0a, Ah1a, Al0a, Al1a)
    K6_ISSUE(1, Ah0b, Ah1b, Al0b, Al1b)
    K6_WAIT(4)
    K6_MFMA(0, Ah0a, Ah1a, Al0a, Al1a)
    K6_ISSUE(2, Ah0a, Ah1a, Al0a, Al1a)
    K6_WAIT(4)
    K6_MFMA(1, Ah0b, Ah1b, Al0b, Al1b)
    K6_ISSUE(3, Ah0b, Ah1b, Al0b, Al1b)
    K6_WAIT(4)
    K6_MFMA(2, Ah0a, Ah1a, Al0a, Al1a)
    K6_ISSUE(4, Ah0a, Ah1a, Al0a, Al1a)
    K6_WAIT(4)
    K6_MFMA(3, Ah0b, Ah1b, Al0b, Al1b)
    K6_ISSUE(5, Ah0b, Ah1b, Al0b, Al1b)
    K6_WAIT(4)
    K6_MFMA(4, Ah0a, Ah1a, Al0a, Al1a)
    K6_ISSUE(6, Ah0a, Ah1a, Al0a, Al1a)
    K6_WAIT(4)
    K6_MFMA(5, Ah0b, Ah1b, Al0b, Al1b)
    K6_WAIT(0)
    K6_MFMA(6, Ah0a, Ah1a, Al0a, Al1a)

#undef K6_ISSUE
#undef K6_WAIT
#undef K6_MFMA

    // ---- epilogue ----
    // 1) sigmoid in place (full EXEC, identical FP expression/order as before)
    #pragma unroll
    for (int j = 0; j < 4; j++) {
        int n = n0 + j * 16 + col;
        float bv = (n < NUM_ENT) ? be[n] : 0.f;
        #pragma unroll
        for (int i = 0; i < 2; i++)
            #pragma unroll
            for (int r = 0; r < 4; r++)
                acc[i][j][r] = sigf(acc[i][j][r] + bv);
    }
    // 2) B LDS is dead for every wave now -> reuse as transpose scratch
    __syncthreads();
    float* tr = ((float*)Bh) + mq * 272;   // per-wave 4 rows x 68 floats (padded)

    // 3) 8 row-groups of 4 rows; each group: quad q's 16 lanes scatter their
    //    16 values, all 64 lanes read back contiguously and store 256B segments
    #pragma unroll
    for (int rg = 0; rg < 8; rg++) {
        int i = rg >> 2, q = rg & 3;
        if (quad == q) {
            #pragma unroll
            for (int j = 0; j < 4; j++)
                #pragma unroll
                for (int r = 0; r < 4; r++)
                    tr[r * 68 + j * 16 + col] = acc[i][j][r];
        }
        f32x4 v = *(const f32x4*)&tr[(lane >> 4) * 68 + (lane & 15) * 4];
        int row = mq * 32 + i * 16 + q * 4 + (lane >> 4);
        int nb = n0 + (lane & 15) * 4;
        if (nb + 3 < NUM_ENT)
            __builtin_nontemporal_store(v, (f32x4*)&out[(size_t)row * NUM_ENT + nb]);
    }
}

extern "C" void kernel_launch(void* const* d_in, const int* in_sizes, int n_in,
                              void* d_out, int out_size, void* d_ws, size_t ws_size,
                              hipStream_t stream) {
    const int*   e1  = (const int*)d_in[0];
    const int*   rel = (const int*)d_in[1];
    const float* emb = (const float*)d_in[2];
    const float* cw  = (const float*)d_in[3];
    const float* cb  = (const float*)d_in[4];
    const float* g0  = (const float*)d_in[5];
    const float* b0  = (const float*)d_in[6];
    const float* g1  = (const float*)d_in[7];
    const float* b1  = (const float*)d_in[8];
    const float* g2  = (const float*)d_in[9];
    const float* b2  = (const float*)d_in[10];
    const float* fcw = (const float*)d_in[11];
    const float* fcb = (const float*)d_in[12];
    const float* be  = (const float*)d_in[13];
    float* ws  = (float*)d_ws;
    float* out = (float*)d_out;

    k1a_bn0<<<64, 256, 0, stream>>>(e1, emb, ws);
    k1b_bn0<<<1, 64, 0, stream>>>(g0, ws);
    k2_conv<<<BATCH, 256, 0, stream>>>(e1, rel, emb, cw, cb, b0, ws);
    k3a_bn1<<<256, 256, 0, stream>>>(ws);
    k3b_bn1<<<1, 256, 0, stream>>>(g1, b1, ws);
    k4_fc  <<<dim3(7, 16, KSPLIT), 256, 0, stream>>>(ws, fcw);
    k5_bn2 <<<KPAD, 256, 0, stream>>>(g2, b2, fcb, ws);
    k6_gemm<<<1563, 1024, 0, stream>>>(ws, emb, be, out);
}

// Round 8
// 435.856 us; speedup vs baseline: 1.5952x; 1.0280x over previous
//
#include <hip/hip_runtime.h>
#include <hip/hip_bf16.h>

// ---------------- problem constants ----------------
#define BATCH   512
#define NUM_ENT 100000
#define EDIM    200
#define KPAD    224         // EDIM padded to multiple of 32
#define OCH     32          // conv out channels
#define OH      8
#define OW      18
#define FCK     4608        // 32*8*18
#define EPSV    1e-5f
#define KSPLIT  4           // k4 K-split factor (K chunk = 1152)

// ---------------- ws layout (float offsets) ----------------
#define WS0   0        // [2]    bn0: mean, rs*g0
#define BN1   8        // [64]   bn1: scale[32], shift[32]
#define K1P   512      // [128]  bn0 per-block partials
#define K3P   704      // [512]  bn1 per-block partials (256 blocks x {sum,sumsq})
#define YCOFF 2048     // [512*32*8*18] = 2359296 -> ends 2361344
#define PART  2361344  // [KSPLIT*512*200] = 409600 -> ends 2770944 (11.08 MB)
// A hi/lo (bf16) overlap the yc region (yc dead after k4):
#define AHI   2048     // 512*224 ushorts = 57344 floats -> ends 59392
#define ALO   59392    // 512*224 ushorts -> ends 116736 (< PART, no overlap)

typedef short bf16x8 __attribute__((ext_vector_type(8)));
typedef float f32x4  __attribute__((ext_vector_type(4)));

__device__ __forceinline__ float sigf(float x) {
    return 1.0f / (1.0f + __expf(-x));
}

__device__ __forceinline__ unsigned short bf16_rn(float v) {
    unsigned int u = __float_as_uint(v);
    unsigned int r = (u + 0x7FFFu + ((u >> 16) & 1u)) >> 16;
    return (unsigned short)r;
}

__device__ __forceinline__ void split_bf16(float v, unsigned short& hi, unsigned short& lo) {
    hi = bf16_rn(v);
    float hf = __uint_as_float(((unsigned int)hi) << 16);
    lo = bf16_rn(v - hf);
}

// A packed-fragment layout: ushort index for element (row b, k j).
// Group g=b>>4, tile t=j>>5, quad q=(j>>3)&3, r=b&15, e=j&7:
//   idx = (g*7 + t)*512 + q*128 + r*8 + e
// => a wave's fragment load (g,t) is base + lane*8 ushorts: contiguous 1 KB.
__device__ __forceinline__ size_t a_idx(int b, int j) {
    return (size_t)(((b >> 4) * 7 + (j >> 5)) * 512 + (((j >> 3) & 3) * 128)
                    + ((b & 15) * 8) + (j & 7));
}

// k1a: bn0 partial sums over gathered embeddings
__global__ __launch_bounds__(256) void k1a_bn0(const int* __restrict__ e1,
                                               const float* __restrict__ emb,
                                               float* __restrict__ ws) {
    __shared__ float red[256], red2[256];
    int tid = threadIdx.x;
    int base = blockIdx.x * 1600;
    float s = 0.f, s2 = 0.f;
    for (int i = base + tid; i < base + 1600; i += 256) {
        int b = i / EDIM;
        int k = i - b * EDIM;
        float v = emb[(size_t)e1[b] * EDIM + k];
        s += v; s2 += v * v;
    }
    red[tid] = s; red2[tid] = s2;
    __syncthreads();
    for (int off = 128; off; off >>= 1) {
        if (tid < off) { red[tid] += red[tid + off]; red2[tid] += red2[tid + off]; }
        __syncthreads();
    }
    if (tid == 0) {
        ws[K1P + 2 * blockIdx.x + 0] = red[0];
        ws[K1P + 2 * blockIdx.x + 1] = red2[0];
    }
}

// k1b: finalize bn0
__global__ __launch_bounds__(64) void k1b_bn0(const float* __restrict__ g0,
                                              float* __restrict__ ws) {
    __shared__ float red[64], red2[64];
    int tid = threadIdx.x;
    red[tid]  = ws[K1P + 2 * tid + 0];
    red2[tid] = ws[K1P + 2 * tid + 1];
    __syncthreads();
    for (int off = 32; off; off >>= 1) {
        if (tid < off) { red[tid] += red[tid + off]; red2[tid] += red2[tid + off]; }
        __syncthreads();
    }
    if (tid == 0) {
        const float inv = 1.0f / (BATCH * EDIM);
        float m = red[0] * inv;
        float var = red2[0] * inv - m * m;
        ws[WS0 + 0] = m;
        ws[WS0 + 1] = rsqrtf(var + EPSV) * g0[0];
    }
}

// k2: relation-indexed 3x3 conv on bn0-normalized x
__global__ __launch_bounds__(256) void k2_conv(const int* __restrict__ e1,
                                               const int* __restrict__ rel,
                                               const float* __restrict__ emb,
                                               const float* __restrict__ cw,
                                               const float* __restrict__ cb,
                                               const float* __restrict__ b0,
                                               float* __restrict__ ws) {
    __shared__ float xs[EDIM];
    __shared__ float wsh[OCH * 9];
    __shared__ float bsh[OCH];
    int b = blockIdx.x, tid = threadIdx.x;
    float m = ws[WS0 + 0], s = ws[WS0 + 1], b0v = b0[0];
    int r = rel[b];
    if (tid < EDIM) xs[tid] = fmaf(emb[(size_t)e1[b] * EDIM + tid] - m, s, b0v);
    for (int i = tid; i < OCH * 9; i += 256) wsh[i] = cw[(size_t)r * OCH * 9 + i];
    if (tid < OCH) bsh[tid] = cb[r * OCH + tid];
    __syncthreads();
    int o = tid >> 3, h = tid & 7;
    float w0 = wsh[o*9+0], w1 = wsh[o*9+1], w2 = wsh[o*9+2];
    float w3 = wsh[o*9+3], w4 = wsh[o*9+4], w5 = wsh[o*9+5];
    float w6 = wsh[o*9+6], w7 = wsh[o*9+7], w8 = wsh[o*9+8];
    float bias = bsh[o];
    float* yout = ws + YCOFF + ((size_t)b * OCH + o) * (OH * OW) + h * OW;
    const float* r0 = &xs[(h + 0) * 20];
    const float* r1 = &xs[(h + 1) * 20];
    const float* r2 = &xs[(h + 2) * 20];
    #pragma unroll
    for (int wd = 0; wd < OW; wd++) {
        float acc = bias;
        acc = fmaf(r0[wd+0], w0, acc); acc = fmaf(r0[wd+1], w1, acc); acc = fmaf(r0[wd+2], w2, acc);
        acc = fmaf(r1[wd+0], w3, acc); acc = fmaf(r1[wd+1], w4, acc); acc = fmaf(r1[wd+2], w5, acc);
        acc = fmaf(r2[wd+0], w6, acc); acc = fmaf(r2[wd+1], w7, acc); acc = fmaf(r2[wd+2], w8, acc);
        yout[wd] = acc;
    }
}

// k3a: bn1 partial stats — 8 slices per channel, 256 blocks
__global__ __launch_bounds__(256) void k3a_bn1(float* __restrict__ ws) {
    __shared__ float red[256], red2[256];
    int o = blockIdx.x >> 3, sl = blockIdx.x & 7;
    int tid = threadIdx.x;
    const float* yc = ws + YCOFF;
    const int per = (BATCH * OH * OW) / 8;   // 9216
    float s = 0.f, s2 = 0.f;
    for (int i = sl * per + tid; i < (sl + 1) * per; i += 256) {
        int b = i / (OH * OW);
        int p = i - b * (OH * OW);
        float v = yc[((size_t)b * OCH + o) * (OH * OW) + p];
        s += v; s2 += v * v;
    }
    red[tid] = s; red2[tid] = s2;
    __syncthreads();
    for (int off = 128; off; off >>= 1) {
        if (tid < off) { red[tid] += red[tid + off]; red2[tid] += red2[tid + off]; }
        __syncthreads();
    }
    if (tid == 0) {
        ws[K3P + 2 * blockIdx.x + 0] = red[0];
        ws[K3P + 2 * blockIdx.x + 1] = red2[0];
    }
}

// k3b: finalize bn1 -> scale/shift
__global__ __launch_bounds__(256) void k3b_bn1(const float* __restrict__ g1,
                                               const float* __restrict__ b1,
                                               float* __restrict__ ws) {
    __shared__ float rs[256], rq[256];
    int tid = threadIdx.x;
    rs[tid] = ws[K3P + 2 * tid + 0];
    rq[tid] = ws[K3P + 2 * tid + 1];
    __syncthreads();
    if (tid < OCH) {
        float sm = 0.f, sq = 0.f;
        #pragma unroll
        for (int sl = 0; sl < 8; sl++) { sm += rs[tid * 8 + sl]; sq += rq[tid * 8 + sl]; }
        const float inv = 1.0f / (BATCH * OH * OW);
        float m = sm * inv;
        float var = sq * inv - m * m;
        float a = rsqrtf(var + EPSV) * g1[tid];
        ws[BN1 + tid] = a;
        ws[BN1 + 32 + tid] = b1[tid] - m * a;
    }
}

// k4: FC GEMM partials (fp32, K-split): 32x32 tile, 448 blocks, K-chunk 64
__global__ __launch_bounds__(256) void k4_fc(float* __restrict__ ws,
                                             const float* __restrict__ fcw) {
    __shared__ float As[64][34];
    __shared__ float Bs[64][34];
    const float* yc = ws + YCOFF;
    const float* bn1p = ws + BN1;
    int tid = threadIdx.x;
    int tx = tid & 15, ty = tid >> 4;      // tx -> n pair, ty -> m pair
    int j0 = blockIdx.x * 32;              // 0..192 (covers 224 padded)
    int m0 = blockIdx.y * 32;
    int kbase = blockIdx.z * (FCK / KSPLIT);
    float* part = ws + PART + (size_t)blockIdx.z * BATCH * EDIM;
    float acc00 = 0.f, acc01 = 0.f, acc10 = 0.f, acc11 = 0.f;

    for (int kc = 0; kc < FCK / KSPLIT; kc += 64) {
        // stage A: 32 m x 64 k, bn1+relu applied; tasks = 32m x 16 kgroups(float4)
        for (int idx = tid; idx < 512; idx += 256) {
            int kg = idx & 15, mm = idx >> 4;
            int gk = kbase + kc + kg * 4;
            int o = gk / 144;                       // 4-group never straddles 144
            float sc = bn1p[o], sh = bn1p[32 + o];
            float4 v = *(const float4*)&yc[(size_t)(m0 + mm) * FCK + gk];
            float t0 = fmaf(v.x, sc, sh); t0 = t0 > 0.f ? t0 : 0.f;
            float t1 = fmaf(v.y, sc, sh); t1 = t1 > 0.f ? t1 : 0.f;
            float t2 = fmaf(v.z, sc, sh); t2 = t2 > 0.f ? t2 : 0.f;
            float t3 = fmaf(v.w, sc, sh); t3 = t3 > 0.f ? t3 : 0.f;
            As[kg * 4 + 0][mm] = t0;
            As[kg * 4 + 1][mm] = t1;
            As[kg * 4 + 2][mm] = t2;
            As[kg * 4 + 3][mm] = t3;
        }
        // stage B: 32 j x 64 k from fcw (zero-fill j >= EDIM)
        for (int idx = tid; idx < 512; idx += 256) {
            int kg = idx & 15, jj = idx >> 4;
            int gj = j0 + jj;
            float4 v = {0.f, 0.f, 0.f, 0.f};
            if (gj < EDIM)
                v = *(const float4*)&fcw[(size_t)gj * FCK + kbase + kc + kg * 4];
            Bs[kg * 4 + 0][jj] = v.x;
            Bs[kg * 4 + 1][jj] = v.y;
            Bs[kg * 4 + 2][jj] = v.z;
            Bs[kg * 4 + 3][jj] = v.w;
        }
        __syncthreads();
        #pragma unroll
        for (int kk = 0; kk < 64; kk++) {
            float2 a = *(const float2*)&As[kk][ty * 2];
            float2 b = *(const float2*)&Bs[kk][tx * 2];
            acc00 = fmaf(a.x, b.x, acc00);
            acc01 = fmaf(a.x, b.y, acc01);
            acc10 = fmaf(a.y, b.x, acc10);
            acc11 = fmaf(a.y, b.y, acc11);
        }
        __syncthreads();
    }
    {
        int m = m0 + ty * 2;
        int gj = j0 + tx * 2;
        if (gj + 0 < EDIM) part[(m + 0) * EDIM + gj + 0] = acc00;
        if (gj + 1 < EDIM) part[(m + 0) * EDIM + gj + 1] = acc01;
        if (gj + 0 < EDIM) part[(m + 1) * EDIM + gj + 0] = acc10;
        if (gj + 1 < EDIM) part[(m + 1) * EDIM + gj + 1] = acc11;
    }
}

// k5: y2 = sum_z part + fc_b; bn2; A = relu(bn2(y2)) split to bf16 hi/lo,
// stored in PACKED-FRAGMENT order (a_idx) so k6's A-loads are contiguous.
__global__ __launch_bounds__(256) void k5_bn2(const float* __restrict__ g2,
                                              const float* __restrict__ b2,
                                              const float* __restrict__ fcb,
                                              float* __restrict__ ws) {
    unsigned short* gAh = (unsigned short*)(ws + AHI);
    unsigned short* gAl = (unsigned short*)(ws + ALO);
    int j = blockIdx.x, tid = threadIdx.x;
    if (j >= EDIM) {   // zero padding columns 200..223
        for (int b = tid; b < BATCH; b += 256) {
            gAh[a_idx(b, j)] = 0;
            gAl[a_idx(b, j)] = 0;
        }
        return;
    }
    __shared__ float red[256], red2[256];
    __shared__ float ss[2];
    const float* part = ws + PART;
    float bias = fcb[j];
    float v0 = bias, v1 = bias;
    #pragma unroll
    for (int z = 0; z < KSPLIT; z++) {
        v0 += part[(size_t)z * BATCH * EDIM + tid * EDIM + j];
        v1 += part[(size_t)z * BATCH * EDIM + (tid + 256) * EDIM + j];
    }
    red[tid] = v0 + v1; red2[tid] = v0 * v0 + v1 * v1;
    __syncthreads();
    for (int off = 128; off; off >>= 1) {
        if (tid < off) { red[tid] += red[tid + off]; red2[tid] += red2[tid + off]; }
        __syncthreads();
    }
    if (tid == 0) {
        const float inv = 1.0f / BATCH;
        float m = red[0] * inv;
        float var = red2[0] * inv - m * m;
        float a = rsqrtf(var + EPSV) * g2[j];
        ss[0] = a;
        ss[1] = b2[j] - m * a;
    }
    __syncthreads();
    float a = ss[0], s = ss[1];
    float r0 = fmaf(v0, a, s); r0 = r0 > 0.f ? r0 : 0.f;
    float r1 = fmaf(v1, a, s); r1 = r1 > 0.f ? r1 : 0.f;
    unsigned short h, l;
    split_bf16(r0, h, l);
    gAh[a_idx(tid, j)] = h;  gAl[a_idx(tid, j)] = l;
    split_bf16(r1, h, l);
    gAh[a_idx(tid + 256, j)] = h;  gAl[a_idx(tid + 256, j)] = l;
}

// k6: logits = sigmoid( A @ emb^T + bias_e ), split-bf16 3-pass MFMA.
// REQUEST-RATE attack:
//  - A in packed-fragment order: each A-fragment load is ONE contiguous 1-KB
//    coalesced wave load (was a 16-segment row-gather -> 16x fewer TA requests)
//  - 512 threads / 8 waves x 64 rows (acc[4][4]): each wave covers 2x m per
//    B-read -> block B-LDS traffic halves; launch_bounds(512,4) + 57 KB LDS
//    -> 2 independent blocks/CU with interleaved phases
//  - B-tile staged once to LDS, one barrier before K-loop
//  - epilogue: sigmoid in place -> per-wave LDS transpose -> nontemporal
//    256B-contiguous f32x4 stores. FP order unchanged -> bit-identical.
__global__ __launch_bounds__(512, 4) void k6_gemm(const float* __restrict__ ws,
                                                  const float* __restrict__ emb,
                                                  const float* __restrict__ be,
                                                  float* __restrict__ out) {
    __shared__ unsigned short Bh[14336];   // 28672 B
    __shared__ unsigned short Bl[14336];   // 28672 B
    const unsigned short* gAh = (const unsigned short*)(ws + AHI);
    const unsigned short* gAl = (const unsigned short*)(ws + ALO);
    int tid = threadIdx.x;
    int n0 = blockIdx.x * 64;

    // ---- stage B tile: 64 ents x 28 k-chunks of 8, fp32 -> split hi/lo ----
    for (int idx = tid; idx < 1792; idx += 512) {
        int col = idx & 15;
        int t   = idx >> 4;          // g*28 + kch
        int g   = t / 28;
        int kch = t - g * 28;
        int gn  = n0 + g * 16 + col;
        float4 va = {0.f, 0.f, 0.f, 0.f};
        float4 vb = {0.f, 0.f, 0.f, 0.f};
        if (gn < NUM_ENT && kch < 25) {                // 25*8 = 200 = EDIM exactly
            const float* row = &emb[(size_t)gn * EDIM + kch * 8];
            va = *(const float4*)row;
            vb = *(const float4*)(row + 4);
        }
        unsigned short h0,h1,h2,h3,h4,h5,h6,h7, l0,l1,l2,l3,l4,l5,l6,l7;
        split_bf16(va.x, h0, l0); split_bf16(va.y, h1, l1);
        split_bf16(va.z, h2, l2); split_bf16(va.w, h3, l3);
        split_bf16(vb.x, h4, l4); split_bf16(vb.y, h5, l5);
        split_bf16(vb.z, h6, l6); split_bf16(vb.w, h7, l7);
        uint4 uh, ul;
        uh.x = (unsigned)h0 | ((unsigned)h1 << 16);
        uh.y = (unsigned)h2 | ((unsigned)h3 << 16);
        uh.z = (unsigned)h4 | ((unsigned)h5 << 16);
        uh.w = (unsigned)h6 | ((unsigned)h7 << 16);
        ul.x = (unsigned)l0 | ((unsigned)l1 << 16);
        ul.y = (unsigned)l2 | ((unsigned)l3 << 16);
        ul.z = (unsigned)l4 | ((unsigned)l5 << 16);
        ul.w = (unsigned)l6 | ((unsigned)l7 << 16);
        *(uint4*)&Bh[idx * 8] = uh;
        *(uint4*)&Bl[idx * 8] = ul;
    }
    __syncthreads();

    // ---- compute: wave wv in [0,8) -> rows wv*64..wv*64+63 ; all 64 n ----
    int lane = tid & 63, col = lane & 15, quad = lane >> 4;
    int wv = tid >> 6;

    f32x4 acc[4][4];
    #pragma unroll
    for (int i = 0; i < 4; i++)
        #pragma unroll
        for (int j = 0; j < 4; j++)
            acc[i][j] = (f32x4){0.f, 0.f, 0.f, 0.f};

    for (int t = 0; t < 7; t++) {                      // 7 K-tiles, no barriers
        bf16x8 ah[4], al[4], bh[4], bl[4];
        #pragma unroll
        for (int i = 0; i < 4; i++) {
            int g = wv * 4 + i;
            size_t aoff = (size_t)((g * 7 + t) << 9) + lane * 8;   // contiguous 1 KB
            ah[i] = *(const bf16x8*)&gAh[aoff];
            al[i] = *(const bf16x8*)&gAl[aoff];
        }
        #pragma unroll
        for (int j = 0; j < 4; j++) {
            int boff = ((j * 28 + t * 4 + quad) * 16 + col) * 8;
            bh[j] = *(const bf16x8*)&Bh[boff];
            bl[j] = *(const bf16x8*)&Bl[boff];
        }
        #pragma unroll
        for (int i = 0; i < 4; i++)
            #pragma unroll
            for (int j = 0; j < 4; j++) {
                acc[i][j] = __builtin_amdgcn_mfma_f32_16x16x32_bf16(ah[i], bh[j], acc[i][j], 0, 0, 0);
                acc[i][j] = __builtin_amdgcn_mfma_f32_16x16x32_bf16(ah[i], bl[j], acc[i][j], 0, 0, 0);
                acc[i][j] = __builtin_amdgcn_mfma_f32_16x16x32_bf16(al[i], bh[j], acc[i][j], 0, 0, 0);
            }
    }

    // ---- epilogue ----
    // 1) sigmoid in place (full EXEC, identical FP expression/order as before)
    #pragma unroll
    for (int j = 0; j < 4; j++) {
        int n = n0 + j * 16 + col;
        float bv = (n < NUM_ENT) ? be[n] : 0.f;
        #pragma unroll
        for (int i = 0; i < 4; i++)
            #pragma unroll
            for (int r = 0; r < 4; r++)
                acc[i][j][r] = sigf(acc[i][j][r] + bv);
    }
    // 2) B LDS is dead for every wave now -> reuse as transpose scratch
    __syncthreads();
    float* tr = ((float*)Bh) + wv * 272;   // per-wave 4 rows x 68 floats (padded)

    // 3) 16 row-groups of 4 rows; each group: quad q's 16 lanes scatter their
    //    16 values, all 64 lanes read back contiguously and store 256B segments
    #pragma unroll
    for (int rg = 0; rg < 16; rg++) {
        int i = rg >> 2, q = rg & 3;
        if (quad == q) {
            #pragma unroll
            for (int j = 0; j < 4; j++)
                #pragma unroll
                for (int r = 0; r < 4; r++)
                    tr[r * 68 + j * 16 + col] = acc[i][j][r];
        }
        f32x4 v = *(const f32x4*)&tr[(lane >> 4) * 68 + (lane & 15) * 4];
        int row = wv * 64 + i * 16 + q * 4 + (lane >> 4);
        int nb = n0 + (lane & 15) * 4;
        if (nb + 3 < NUM_ENT)
            __builtin_nontemporal_store(v, (f32x4*)&out[(size_t)row * NUM_ENT + nb]);
    }
}

extern "C" void kernel_launch(void* const* d_in, const int* in_sizes, int n_in,
                              void* d_out, int out_size, void* d_ws, size_t ws_size,
                              hipStream_t stream) {
    const int*   e1  = (const int*)d_in[0];
    const int*   rel = (const int*)d_in[1];
    const float* emb = (const float*)d_in[2];
    const float* cw  = (const float*)d_in[3];
    const float* cb  = (const float*)d_in[4];
    const float* g0  = (const float*)d_in[5];
    const float* b0  = (const float*)d_in[6];
    const float* g1  = (const float*)d_in[7];
    const float* b1  = (const float*)d_in[8];
    const float* g2  = (const float*)d_in[9];
    const float* b2  = (const float*)d_in[10];
    const float* fcw = (const float*)d_in[11];
    const float* fcb = (const float*)d_in[12];
    const float* be  = (const float*)d_in[13];
    float* ws  = (float*)d_ws;
    float* out = (float*)d_out;

    k1a_bn0<<<64, 256, 0, stream>>>(e1, emb, ws);
    k1b_bn0<<<1, 64, 0, stream>>>(g0, ws);
    k2_conv<<<BATCH, 256, 0, stream>>>(e1, rel, emb, cw, cb, b0, ws);
    k3a_bn1<<<256, 256, 0, stream>>>(ws);
    k3b_bn1<<<1, 256, 0, stream>>>(g1, b1, ws);
    k4_fc  <<<dim3(7, 16, KSPLIT), 256, 0, stream>>>(ws, fcw);
    k5_bn2 <<<KPAD, 256, 0, stream>>>(g2, b2, fcb, ws);
    k6_gemm<<<1563, 512, 0, stream>>>(ws, emb, be, out);
}